// Round 6
// baseline (2713.885 us; speedup 1.0000x reference)
//
#include <hip/hip_runtime.h>
#include <stdint.h>

#define VOCAB 32000
#define EMB   1024
#define HID   1024
#define BATCH 16
#define SEQ   256
#define MROWS (SEQ*BATCH)   // 4096

typedef unsigned short u16;
typedef uint32_t u32;
typedef __bf16 bf16x8 __attribute__((ext_vector_type(8)));
typedef float  f32x4  __attribute__((ext_vector_type(4)));
typedef u32    u32x4  __attribute__((ext_vector_type(4)));

static __device__ __forceinline__ u16 f2bf(float f) {
  union { float f; uint32_t u; } v; v.f = f;
  return (u16)((v.u + 0x7FFFu + ((v.u >> 16) & 1u)) >> 16);  // RNE
}

static __device__ __forceinline__ f32x4 MFMA(bf16x8 a, bf16x8 b, f32x4 c) {
  return __builtin_amdgcn_mfma_f32_16x16x32_bf16(a, b, c, 0, 0, 0);
}

// ---- coherent (XCD-bypass) memory helpers ----
static __device__ __forceinline__ void load8_coh(const void* p, bf16x8* r) {
  asm volatile(
    "global_load_dwordx4 %0, %8, off sc0 sc1\n\t"
    "global_load_dwordx4 %1, %8, off offset:64 sc0 sc1\n\t"
    "global_load_dwordx4 %2, %8, off offset:128 sc0 sc1\n\t"
    "global_load_dwordx4 %3, %8, off offset:192 sc0 sc1\n\t"
    "global_load_dwordx4 %4, %8, off offset:256 sc0 sc1\n\t"
    "global_load_dwordx4 %5, %8, off offset:320 sc0 sc1\n\t"
    "global_load_dwordx4 %6, %8, off offset:384 sc0 sc1\n\t"
    "global_load_dwordx4 %7, %8, off offset:448 sc0 sc1\n\t"
    "s_waitcnt vmcnt(0)"
    : "=&v"(r[0]), "=&v"(r[1]), "=&v"(r[2]), "=&v"(r[3]),
      "=&v"(r[4]), "=&v"(r[5]), "=&v"(r[6]), "=&v"(r[7])
    : "v"(p) : "memory");
}

static __device__ __forceinline__ void store_u16_coh(u16* p, u16 v) {
  asm volatile("global_store_short %0, %1, off sc0 sc1"
               :: "v"(p), "v"((u32)v) : "memory");
}
static __device__ __forceinline__ void wait_vm0() {
  asm volatile("s_waitcnt vmcnt(0)" ::: "memory");
}

// poll a 128B flag line (64 u16 slots): 1 if ALL slots equal splatted pattern
static __device__ __forceinline__ int flags_ready128(const void* p, u32 pat) {
  u32x4 r0, r1, r2, r3, r4, r5, r6, r7;
  asm volatile(
    "global_load_dwordx4 %0, %8, off sc0 sc1\n\t"
    "global_load_dwordx4 %1, %8, off offset:16 sc0 sc1\n\t"
    "global_load_dwordx4 %2, %8, off offset:32 sc0 sc1\n\t"
    "global_load_dwordx4 %3, %8, off offset:48 sc0 sc1\n\t"
    "global_load_dwordx4 %4, %8, off offset:64 sc0 sc1\n\t"
    "global_load_dwordx4 %5, %8, off offset:80 sc0 sc1\n\t"
    "global_load_dwordx4 %6, %8, off offset:96 sc0 sc1\n\t"
    "global_load_dwordx4 %7, %8, off offset:112 sc0 sc1\n\t"
    "s_waitcnt vmcnt(0)"
    : "=&v"(r0), "=&v"(r1), "=&v"(r2), "=&v"(r3),
      "=&v"(r4), "=&v"(r5), "=&v"(r6), "=&v"(r7)
    : "v"(p) : "memory");
  u32 m = (r0[0]^pat)|(r0[1]^pat)|(r0[2]^pat)|(r0[3]^pat)
        | (r1[0]^pat)|(r1[1]^pat)|(r1[2]^pat)|(r1[3]^pat)
        | (r2[0]^pat)|(r2[1]^pat)|(r2[2]^pat)|(r2[3]^pat)
        | (r3[0]^pat)|(r3[1]^pat)|(r3[2]^pat)|(r3[3]^pat)
        | (r4[0]^pat)|(r4[1]^pat)|(r4[2]^pat)|(r4[3]^pat)
        | (r5[0]^pat)|(r5[1]^pat)|(r5[2]^pat)|(r5[3]^pat)
        | (r6[0]^pat)|(r6[1]^pat)|(r6[2]^pat)|(r6[3]^pat)
        | (r7[0]^pat)|(r7[1]^pat)|(r7[2]^pat)|(r7[3]^pat);
  return m == 0u;
}

// ---------------- converts ----------------

// hidden -> bf16 init vectors; also zero the flag region (16384 u32 = 64KB)
__global__ void cvt_hidden(const float* __restrict__ hidden,
                           u16* __restrict__ h0i, u16* __restrict__ h1i,
                           unsigned* __restrict__ flags) {
  int i = blockIdx.x * 256 + threadIdx.x;
  if (i < 16384) flags[i] = 0u;
  if (i < BATCH * HID)            h0i[i] = f2bf(hidden[i]);
  else if (i < 2 * BATCH * HID)   h1i[i - BATCH * HID] = f2bf(hidden[i]);
}

// (K=1024 x N=1024) f32 row-major  ->  (N,K) bf16
__global__ void transpose_cvt(const float* __restrict__ in, u16* __restrict__ out) {
  __shared__ float tile[32][33];
  int bx = blockIdx.x * 32;   // N
  int by = blockIdx.y * 32;   // K
  int tx = threadIdx.x, ty = threadIdx.y;   // (32,8)
  #pragma unroll
  for (int i = 0; i < 32; i += 8)
    tile[ty + i][tx] = in[(size_t)(by + ty + i) * HID + bx + tx];
  __syncthreads();
  #pragma unroll
  for (int i = 0; i < 32; i += 8)
    out[(size_t)(bx + ty + i) * HID + by + tx] = f2bf(tile[tx][ty + i]);
}

__global__ void cvt_emb(const float4* __restrict__ in, ushort4* __restrict__ out, int n4) {
  int stride = gridDim.x * blockDim.x;
  for (int i = blockIdx.x * blockDim.x + threadIdx.x; i < n4; i += stride) {
    float4 v = in[i];
    ushort4 o; o.x = f2bf(v.x); o.y = f2bf(v.y); o.z = f2bf(v.z); o.w = f2bf(v.w);
    out[i] = o;
  }
}

__global__ void gather_emb(const int* __restrict__ x, const float* __restrict__ embW,
                           u16* __restrict__ E) {
  int r = blockIdx.x;               // 0..4095
  int b = r & 15, t = r >> 4;
  int idx = x[b * SEQ + t];
  const float4* src = (const float4*)(embW + (size_t)idx * EMB);
  ushort4* dst = (ushort4*)(E + (size_t)r * EMB);
  float4 v = src[threadIdx.x];
  ushort4 o; o.x = f2bf(v.x); o.y = f2bf(v.y); o.z = f2bf(v.z); o.w = f2bf(v.w);
  dst[threadIdx.x] = o;
}

// ---------------- 128x128 MFMA GEMM, C = A(MxK) @ B(NxK)^T + bias ----------------
template <int OUTMODE>
__global__ __launch_bounds__(256) void gemm_bt(
    const u16* __restrict__ A, const u16* __restrict__ B,
    const float* __restrict__ bias, float* __restrict__ C,
    int M, int N, int K)
{
  __shared__ __align__(16) char lds[32768];
  char* As = lds;
  char* Bs = lds + 16384;
  const int tid  = threadIdx.x;
  const int lane = tid & 63;
  const int wave = tid >> 6;
  const int wr = wave >> 1, wc = wave & 1;
  const int bm = blockIdx.y * 128;
  const int bn = blockIdx.x * 128;
  const int srow = tid >> 3;
  const int swc  = (tid & 7) ^ (srow & 7);

  f32x4 acc[4][4];
  #pragma unroll
  for (int i = 0; i < 4; ++i)
    #pragma unroll
    for (int j = 0; j < 4; ++j) acc[i][j] = (f32x4){0.f, 0.f, 0.f, 0.f};

  const u16* Ab = A + (size_t)(bm + srow) * K + swc * 8;
  const u16* Bb = B + (size_t)(bn + srow) * K + swc * 8;
  const size_t rstep = (size_t)32 * K;

  for (int k0 = 0; k0 < K; k0 += 64) {
    #pragma unroll
    for (int i = 0; i < 4; ++i) {
      __builtin_amdgcn_global_load_lds(
          (const __attribute__((address_space(1))) void*)(Ab + i * rstep + k0),
          (__attribute__((address_space(3))) void*)(As + i * 4096 + wave * 1024),
          16, 0, 0);
      __builtin_amdgcn_global_load_lds(
          (const __attribute__((address_space(1))) void*)(Bb + i * rstep + k0),
          (__attribute__((address_space(3))) void*)(Bs + i * 4096 + wave * 1024),
          16, 0, 0);
    }
    __syncthreads();
    #pragma unroll
    for (int ks = 0; ks < 2; ++ks) {
      bf16x8 af[4], bq[4];
      #pragma unroll
      for (int mi = 0; mi < 4; ++mi) {
        int row = wr * 64 + mi * 16 + (lane & 15);
        int c = (ks * 4 + (lane >> 4)) ^ (row & 7);
        af[mi] = *(const bf16x8*)(As + row * 128 + c * 16);
      }
      #pragma unroll
      for (int ni = 0; ni < 4; ++ni) {
        int row = wc * 64 + ni * 16 + (lane & 15);
        int c = (ks * 4 + (lane >> 4)) ^ (row & 7);
        bq[ni] = *(const bf16x8*)(Bs + row * 128 + c * 16);
      }
      #pragma unroll
      for (int mi = 0; mi < 4; ++mi)
        #pragma unroll
        for (int ni = 0; ni < 4; ++ni)
          acc[mi][ni] = MFMA(af[mi], bq[ni], acc[mi][ni]);
    }
    __syncthreads();
  }

  #pragma unroll
  for (int mi = 0; mi < 4; ++mi) {
    #pragma unroll
    for (int ni = 0; ni < 4; ++ni) {
      const int col = bn + wc * 64 + ni * 16 + (lane & 15);
      const float bv = bias[col];
      #pragma unroll
      for (int j = 0; j < 4; ++j) {
        const int row = bm + wr * 64 + mi * 16 + ((lane >> 4) << 2) + j;
        const float v = acc[mi][ni][j] + bv;
        size_t off;
        if (OUTMODE == 0)
          off = (size_t)row * N + col;
        else
          off = (size_t)(row & 15) * ((size_t)SEQ * VOCAB) + (size_t)(row >> 4) * VOCAB + col;
        C[off] = v;
      }
    }
  }
}

// ---------------- fused 2-layer recurrence: register weights, minimal coherent traffic ----
// 24 blocks x 512 threads. Blocks 0..7: layer 0 (128 cols each; waves = (K-quarter q, col-half ct)).
// Blocks 8..23: layer 1 (64 cols each; waves = (matrix m, K-quarter q); loads exactly dedup'd).
// Weights live in REGISTERS (b[4][8] bf16x8 per wave). Flags: per-wave u16 slots, 64 per
// 128B line per step. f0[s]: 8 blk x 8 waves; f1[t]: 16 blk x 4 finish waves. Values s+1.
#define L0NB 8
#define L1NB 16
#define RNB  (L0NB + L1NB)

__global__ __launch_bounds__(512) void recurrence(
    const u16* __restrict__ Wh0T, const u16* __restrict__ Wx1T, const u16* __restrict__ Wh1T,
    const float* __restrict__ X0,       // 4096x1024 f32, includes b0
    const float* __restrict__ b1,
    const u16* __restrict__ h0init, const u16* __restrict__ h1init,
    u16* H0, u16* H1,                   // 4096x1024 bf16, coherent-exchanged
    float* __restrict__ hidOut,         // (2,16,1024) f32 at d_out tail
    char* flags)                        // 64KB: f0 at 0, f1 at +32KB
{
  __shared__ __align__(16) f32x4 comb[8][4][64];   // 32KB partial-sum exchange
  const int tid  = threadIdx.x;
  const int lane = tid & 63;
  const int w    = tid >> 6;           // 0..7
  const int l15  = lane & 15;
  const int lk   = lane >> 4;          // 0..3
  char* f0 = flags;
  char* f1 = flags + 32768;

  if (blockIdx.x < L0NB) {
    // ---------------- layer 0 ----------------
    const int blk = blockIdx.x;
    const int q  = w >> 1;             // K-quarter
    const int ct = w & 1;              // col-half (64 cols)
    const int colb = blk * 128 + ct * 64;
    bf16x8 b[4][8];                    // weights in registers
    #pragma unroll
    for (int cg = 0; cg < 4; ++cg) {
      const u16* wp = Wh0T + (size_t)(colb + cg * 16 + l15) * HID + q * 256 + lk * 8;
      #pragma unroll
      for (int ksl = 0; ksl < 8; ++ksl) b[cg][ksl] = *(const bf16x8*)(wp + ksl * 32);
    }
    const int mycol = colb + q * 16 + l15;   // finish column (cg = q)
    for (int s = 0; s < SEQ; ++s) {
      float xv[4];
      #pragma unroll
      for (int j = 0; j < 4; ++j)      // issue X0 loads before the poll (hidden under spin)
        xv[j] = X0[(size_t)(s * BATCH + lk * 4 + j) * HID + mycol];
      if (s > 0) {
        const u32 pat = (u32)s * 0x10001u;
        while (!flags_ready128(f0 + (size_t)(s - 1) * 128, pat)) {}
      }
      const u16* hsrc = (s == 0) ? h0init : (H0 + (size_t)(s - 1) * BATCH * HID);
      bf16x8 a[8];
      load8_coh((const char*)hsrc + l15 * 2048 + q * 512 + lk * 16, a);
      f32x4 acc[4];
      #pragma unroll
      for (int cg = 0; cg < 4; ++cg) acc[cg] = (f32x4){0.f, 0.f, 0.f, 0.f};
      #pragma unroll
      for (int ksl = 0; ksl < 8; ++ksl)
        #pragma unroll
        for (int cg = 0; cg < 4; ++cg)
          acc[cg] = MFMA(a[ksl], b[cg][ksl], acc[cg]);
      #pragma unroll
      for (int cg = 0; cg < 4; ++cg) comb[w][cg][lane] = acc[cg];
      __syncthreads();
      // finish cg = q for col-half ct: sum waves (q', ct) = indices q'*2+ct
      f32x4 r = (comb[ct][q][lane] + comb[2 + ct][q][lane])
              + (comb[4 + ct][q][lane] + comb[6 + ct][q][lane]);
      #pragma unroll
      for (int j = 0; j < 4; ++j) {
        float v = tanhf(r[j] + xv[j]);
        store_u16_coh(H0 + (size_t)(s * BATCH + lk * 4 + j) * HID + mycol, f2bf(v));
        if (s == SEQ - 1) hidOut[(size_t)(lk * 4 + j) * HID + mycol] = v;
      }
      wait_vm0();
      if (lane == 0)
        store_u16_coh((u16*)(f0 + (size_t)s * 128) + (blk * 8 + w), (u16)(s + 1));
      // comb reuse safe: advancing past f0[s] poll implies all 8 waves finished reads
    }
  } else {
    // ---------------- layer 1 ----------------
    const int blk = blockIdx.x - L0NB;   // 0..15
    const int m = w >> 2;                // 0: Wx1 (vs h0(t)), 1: Wh1 (vs h1(t-1))
    const int q = w & 3;                 // K-quarter
    const int colb = blk * 64;
    const u16* Wm = m ? Wh1T : Wx1T;
    bf16x8 b[4][8];
    #pragma unroll
    for (int cg = 0; cg < 4; ++cg) {
      const u16* wp = Wm + (size_t)(colb + cg * 16 + l15) * HID + q * 256 + lk * 8;
      #pragma unroll
      for (int ksl = 0; ksl < 8; ++ksl) b[cg][ksl] = *(const bf16x8*)(wp + ksl * 32);
    }
    const int mycol = colb + q * 16 + l15;   // finish col for m==0 waves
    const float bv = b1[mycol];
    for (int t = 0; t < SEQ; ++t) {
      const u16* hsrc;
      if (m == 0) {
        const u32 pat = (u32)(t + 1) * 0x10001u;
        while (!flags_ready128(f0 + (size_t)t * 128, pat)) {}
        hsrc = H0 + (size_t)t * BATCH * HID;
      } else if (t == 0) {
        hsrc = h1init;
      } else {
        const u32 pat = (u32)t * 0x10001u;
        while (!flags_ready128(f1 + (size_t)(t - 1) * 128, pat)) {}
        hsrc = H1 + (size_t)(t - 1) * BATCH * HID;
      }
      bf16x8 a[8];
      load8_coh((const char*)hsrc + l15 * 2048 + q * 512 + lk * 16, a);
      f32x4 acc[4];
      #pragma unroll
      for (int cg = 0; cg < 4; ++cg) acc[cg] = (f32x4){0.f, 0.f, 0.f, 0.f};
      #pragma unroll
      for (int ksl = 0; ksl < 8; ++ksl)
        #pragma unroll
        for (int cg = 0; cg < 4; ++cg)
          acc[cg] = MFMA(a[ksl], b[cg][ksl], acc[cg]);
      #pragma unroll
      for (int cg = 0; cg < 4; ++cg) comb[w][cg][lane] = acc[cg];
      __syncthreads();
      if (m == 0) {   // finish cg = q: sum all 8 waves
        f32x4 r = ((comb[0][q][lane] + comb[1][q][lane])
                 + (comb[2][q][lane] + comb[3][q][lane]))
                + ((comb[4][q][lane] + comb[5][q][lane])
                 + (comb[6][q][lane] + comb[7][q][lane]));
        #pragma unroll
        for (int j = 0; j < 4; ++j) {
          float v = tanhf(r[j] + bv);
          store_u16_coh(H1 + (size_t)(t * BATCH + lk * 4 + j) * HID + mycol, f2bf(v));
          if (t == SEQ - 1)
            hidOut[(size_t)(BATCH * HID) + (size_t)(lk * 4 + j) * HID + mycol] = v;
        }
        wait_vm0();
        if (lane == 0)
          store_u16_coh((u16*)(f1 + (size_t)t * 128) + (blk * 4 + q), (u16)(t + 1));
      }
      __syncthreads();   // protect comb reuse (m=1 waves advance via f1, not f0)
    }
  }
}

// ---------------- launch ----------------
extern "C" void kernel_launch(void* const* d_in, const int* in_sizes, int n_in,
                              void* d_out, int out_size, void* d_ws, size_t ws_size,
                              hipStream_t stream) {
  const int*   x      = (const int*)  d_in[0];
  const float* hidden = (const float*)d_in[1];
  const float* embW   = (const float*)d_in[2];
  const float* Wx0    = (const float*)d_in[3];
  const float* Wh0    = (const float*)d_in[4];
  const float* b0     = (const float*)d_in[5];
  const float* Wx1    = (const float*)d_in[6];
  const float* Wh1    = (const float*)d_in[7];
  const float* b1     = (const float*)d_in[8];
  const float* outb   = (const float*)d_in[9];
  float* out = (float*)d_out;

  char* ws = (char*)d_ws;
  size_t off = 0;
  auto alloc = [&](size_t bytes) {
    char* p = ws + off; off += (bytes + 255) & ~(size_t)255; return p;
  };
  u16*   embB = (u16*)  alloc((size_t)VOCAB * EMB * 2);
  u16*   Wx0T = (u16*)  alloc((size_t)EMB * HID * 2);
  u16*   Wh0T = (u16*)  alloc((size_t)HID * HID * 2);
  u16*   Wx1T = (u16*)  alloc((size_t)HID * HID * 2);
  u16*   Wh1T = (u16*)  alloc((size_t)HID * HID * 2);
  u16*   E    = (u16*)  alloc((size_t)MROWS * EMB * 2);
  float* X0f  = (float*)alloc((size_t)MROWS * HID * 4);
  u16*   H0   = (u16*)  alloc((size_t)MROWS * HID * 2);
  u16*   H1   = (u16*)  alloc((size_t)MROWS * HID * 2);
  u16*   h0i  = (u16*)  alloc((size_t)BATCH * HID * 2);
  u16*   h1i  = (u16*)  alloc((size_t)BATCH * HID * 2);
  char*  flags = (char*)alloc(65536);   // f0[256 lines] + f1[256 lines], 128B each
  if (off > ws_size) return;

  cvt_hidden<<<dim3(128), dim3(256), 0, stream>>>(hidden, h0i, h1i, (unsigned*)flags);

  dim3 tb(32, 8), tg(32, 32);
  transpose_cvt<<<tg, tb, 0, stream>>>(Wx0, Wx0T);
  transpose_cvt<<<tg, tb, 0, stream>>>(Wh0, Wh0T);
  transpose_cvt<<<tg, tb, 0, stream>>>(Wx1, Wx1T);
  transpose_cvt<<<tg, tb, 0, stream>>>(Wh1, Wh1T);

  cvt_emb<<<dim3(2048), dim3(256), 0, stream>>>(
      (const float4*)embW, (ushort4*)embB, (int)((size_t)VOCAB * EMB / 4));
  gather_emb<<<dim3(MROWS), dim3(256), 0, stream>>>(x, embW, E);

  // X0 = E @ Wx0^T + b0   (4096x1024)
  gemm_bt<0><<<dim3(HID / 128, MROWS / 128), dim3(256), 0, stream>>>(
      E, Wx0T, b0, X0f, MROWS, HID, EMB);

  // fused recurrence: writes H0, H1 and final hidden into d_out tail
  recurrence<<<dim3(RNB), dim3(512), 0, stream>>>(
      Wh0T, Wx1T, Wh1T, X0f, b1, h0i, h1i, H0, H1,
      out + (size_t)BATCH * SEQ * VOCAB, flags);

  // logits = H1 @ emb^T + out_b   (4096x32000, remapped to (B,T,V))
  gemm_bt<1><<<dim3(VOCAB / 128, MROWS / 128), dim3(256), 0, stream>>>(
      H1, embB, outb, out, MROWS, VOCAB, EMB);
}

// Round 8
// 1970.750 us; speedup vs baseline: 1.3771x; 1.3771x over previous
//
#include <hip/hip_runtime.h>
#include <stdint.h>

#define VOCAB 32000
#define EMB   1024
#define HID   1024
#define BATCH 16
#define SEQ   256
#define MROWS (SEQ*BATCH)   // 4096

typedef unsigned short u16;
typedef uint32_t u32;
typedef __bf16 bf16x8 __attribute__((ext_vector_type(8)));
typedef float  f32x4  __attribute__((ext_vector_type(4)));
typedef u32    u32x4  __attribute__((ext_vector_type(4)));

static __device__ __forceinline__ u16 f2bf(float f) {
  union { float f; uint32_t u; } v; v.f = f;
  return (u16)((v.u + 0x7FFFu + ((v.u >> 16) & 1u)) >> 16);  // RNE
}

static __device__ __forceinline__ f32x4 MFMA(bf16x8 a, bf16x8 b, f32x4 c) {
  return __builtin_amdgcn_mfma_f32_16x16x32_bf16(a, b, c, 0, 0, 0);
}

// ---- coherent (device-scope, L1/L2-bypass) memory helpers ----
static __device__ __forceinline__ void load8_coh(const void* p, bf16x8* r) {
  asm volatile(
    "global_load_dwordx4 %0, %8, off sc0 sc1\n\t"
    "global_load_dwordx4 %1, %8, off offset:64 sc0 sc1\n\t"
    "global_load_dwordx4 %2, %8, off offset:128 sc0 sc1\n\t"
    "global_load_dwordx4 %3, %8, off offset:192 sc0 sc1\n\t"
    "global_load_dwordx4 %4, %8, off offset:256 sc0 sc1\n\t"
    "global_load_dwordx4 %5, %8, off offset:320 sc0 sc1\n\t"
    "global_load_dwordx4 %6, %8, off offset:384 sc0 sc1\n\t"
    "global_load_dwordx4 %7, %8, off offset:448 sc0 sc1\n\t"
    "s_waitcnt vmcnt(0)"
    : "=&v"(r[0]), "=&v"(r[1]), "=&v"(r[2]), "=&v"(r[3]),
      "=&v"(r[4]), "=&v"(r[5]), "=&v"(r[6]), "=&v"(r[7])
    : "v"(p) : "memory");
}

static __device__ __forceinline__ void load16_coh(const void* p, bf16x8* r) {
  asm volatile(
    "global_load_dwordx4 %0, %16, off sc0 sc1\n\t"
    "global_load_dwordx4 %1, %16, off offset:64 sc0 sc1\n\t"
    "global_load_dwordx4 %2, %16, off offset:128 sc0 sc1\n\t"
    "global_load_dwordx4 %3, %16, off offset:192 sc0 sc1\n\t"
    "global_load_dwordx4 %4, %16, off offset:256 sc0 sc1\n\t"
    "global_load_dwordx4 %5, %16, off offset:320 sc0 sc1\n\t"
    "global_load_dwordx4 %6, %16, off offset:384 sc0 sc1\n\t"
    "global_load_dwordx4 %7, %16, off offset:448 sc0 sc1\n\t"
    "global_load_dwordx4 %8, %16, off offset:512 sc0 sc1\n\t"
    "global_load_dwordx4 %9, %16, off offset:576 sc0 sc1\n\t"
    "global_load_dwordx4 %10, %16, off offset:640 sc0 sc1\n\t"
    "global_load_dwordx4 %11, %16, off offset:704 sc0 sc1\n\t"
    "global_load_dwordx4 %12, %16, off offset:768 sc0 sc1\n\t"
    "global_load_dwordx4 %13, %16, off offset:832 sc0 sc1\n\t"
    "global_load_dwordx4 %14, %16, off offset:896 sc0 sc1\n\t"
    "global_load_dwordx4 %15, %16, off offset:960 sc0 sc1\n\t"
    "s_waitcnt vmcnt(0)"
    : "=&v"(r[0]), "=&v"(r[1]), "=&v"(r[2]), "=&v"(r[3]),
      "=&v"(r[4]), "=&v"(r[5]), "=&v"(r[6]), "=&v"(r[7]),
      "=&v"(r[8]), "=&v"(r[9]), "=&v"(r[10]), "=&v"(r[11]),
      "=&v"(r[12]), "=&v"(r[13]), "=&v"(r[14]), "=&v"(r[15])
    : "v"(p) : "memory");
}

// two coherent 16B loads (for A-tile staging in the logits consumer)
static __device__ __forceinline__ void load2_coh16(const void* p0, const void* p1,
                                                   u32x4* r0, u32x4* r1) {
  asm volatile(
    "global_load_dwordx4 %0, %2, off sc0 sc1\n\t"
    "global_load_dwordx4 %1, %3, off sc0 sc1\n\t"
    "s_waitcnt vmcnt(0)"
    : "=&v"(*r0), "=&v"(*r1) : "v"(p0), "v"(p1) : "memory");
}

static __device__ __forceinline__ void store_u16_coh(u16* p, u16 v) {
  asm volatile("global_store_short %0, %1, off sc0 sc1"
               :: "v"(p), "v"((u32)v) : "memory");
}
static __device__ __forceinline__ void wait_vm0() {
  asm volatile("s_waitcnt vmcnt(0)" ::: "memory");
}

// poll a 64B flag line (32 u16 slots): 1 if ALL slots equal the splatted pattern
static __device__ __forceinline__ int flags_ready(const void* p, u32 pat) {
  u32x4 a, b, c, d;
  asm volatile(
    "global_load_dwordx4 %0, %4, off sc0 sc1\n\t"
    "global_load_dwordx4 %1, %4, off offset:16 sc0 sc1\n\t"
    "global_load_dwordx4 %2, %4, off offset:32 sc0 sc1\n\t"
    "global_load_dwordx4 %3, %4, off offset:48 sc0 sc1\n\t"
    "s_waitcnt vmcnt(0)"
    : "=&v"(a), "=&v"(b), "=&v"(c), "=&v"(d)
    : "v"(p) : "memory");
  u32 m = (a[0]^pat)|(a[1]^pat)|(a[2]^pat)|(a[3]^pat)
        | (b[0]^pat)|(b[1]^pat)|(b[2]^pat)|(b[3]^pat)
        | (c[0]^pat)|(c[1]^pat)|(c[2]^pat)|(c[3]^pat)
        | (d[0]^pat)|(d[1]^pat)|(d[2]^pat)|(d[3]^pat);
  return m == 0u;
}

// ---------------- converts ----------------

// hidden -> bf16 init vectors; also zero the flag region (16384 u32 = 64KB)
__global__ void cvt_hidden(const float* __restrict__ hidden,
                           u16* __restrict__ h0i, u16* __restrict__ h1i,
                           unsigned* __restrict__ flags) {
  int i = blockIdx.x * 256 + threadIdx.x;
  if (i < 16384) flags[i] = 0u;
  if (i < BATCH * HID)            h0i[i] = f2bf(hidden[i]);
  else if (i < 2 * BATCH * HID)   h1i[i - BATCH * HID] = f2bf(hidden[i]);
}

// (K=1024 x N=1024) f32 row-major  ->  (N,K) bf16
__global__ void transpose_cvt(const float* __restrict__ in, u16* __restrict__ out) {
  __shared__ float tile[32][33];
  int bx = blockIdx.x * 32;   // N
  int by = blockIdx.y * 32;   // K
  int tx = threadIdx.x, ty = threadIdx.y;   // (32,8)
  #pragma unroll
  for (int i = 0; i < 32; i += 8)
    tile[ty + i][tx] = in[(size_t)(by + ty + i) * HID + bx + tx];
  __syncthreads();
  #pragma unroll
  for (int i = 0; i < 32; i += 8)
    out[(size_t)(bx + ty + i) * HID + by + tx] = f2bf(tile[tx][ty + i]);
}

__global__ void cvt_emb(const float4* __restrict__ in, ushort4* __restrict__ out, int n4) {
  int stride = gridDim.x * blockDim.x;
  for (int i = blockIdx.x * blockDim.x + threadIdx.x; i < n4; i += stride) {
    float4 v = in[i];
    ushort4 o; o.x = f2bf(v.x); o.y = f2bf(v.y); o.z = f2bf(v.z); o.w = f2bf(v.w);
    out[i] = o;
  }
}

__global__ void gather_emb(const int* __restrict__ x, const float* __restrict__ embW,
                           u16* __restrict__ E) {
  int r = blockIdx.x;               // 0..4095
  int b = r & 15, t = r >> 4;
  int idx = x[b * SEQ + t];
  const float4* src = (const float4*)(embW + (size_t)idx * EMB);
  ushort4* dst = (ushort4*)(E + (size_t)r * EMB);
  float4 v = src[threadIdx.x];
  ushort4 o; o.x = f2bf(v.x); o.y = f2bf(v.y); o.z = f2bf(v.z); o.w = f2bf(v.w);
  dst[threadIdx.x] = o;
}

// ---------------- 128x128 MFMA GEMM, C = A(MxK) @ B(NxK)^T + bias (X0 only) ----------------
template <int OUTMODE>
__global__ __launch_bounds__(256) void gemm_bt(
    const u16* __restrict__ A, const u16* __restrict__ B,
    const float* __restrict__ bias, float* __restrict__ C,
    int M, int N, int K)
{
  __shared__ __align__(16) char lds[32768];
  char* As = lds;
  char* Bs = lds + 16384;
  const int tid  = threadIdx.x;
  const int lane = tid & 63;
  const int wave = tid >> 6;
  const int wr = wave >> 1, wc = wave & 1;
  const int bm = blockIdx.y * 128;
  const int bn = blockIdx.x * 128;
  const int srow = tid >> 3;
  const int swc  = (tid & 7) ^ (srow & 7);

  f32x4 acc[4][4];
  #pragma unroll
  for (int i = 0; i < 4; ++i)
    #pragma unroll
    for (int j = 0; j < 4; ++j) acc[i][j] = (f32x4){0.f, 0.f, 0.f, 0.f};

  const u16* Ab = A + (size_t)(bm + srow) * K + swc * 8;
  const u16* Bb = B + (size_t)(bn + srow) * K + swc * 8;
  const size_t rstep = (size_t)32 * K;

  for (int k0 = 0; k0 < K; k0 += 64) {
    #pragma unroll
    for (int i = 0; i < 4; ++i) {
      __builtin_amdgcn_global_load_lds(
          (const __attribute__((address_space(1))) void*)(Ab + i * rstep + k0),
          (__attribute__((address_space(3))) void*)(As + i * 4096 + wave * 1024),
          16, 0, 0);
      __builtin_amdgcn_global_load_lds(
          (const __attribute__((address_space(1))) void*)(Bb + i * rstep + k0),
          (__attribute__((address_space(3))) void*)(Bs + i * 4096 + wave * 1024),
          16, 0, 0);
    }
    __syncthreads();
    #pragma unroll
    for (int ks = 0; ks < 2; ++ks) {
      bf16x8 af[4], bq[4];
      #pragma unroll
      for (int mi = 0; mi < 4; ++mi) {
        int row = wr * 64 + mi * 16 + (lane & 15);
        int c = (ks * 4 + (lane >> 4)) ^ (row & 7);
        af[mi] = *(const bf16x8*)(As + row * 128 + c * 16);
      }
      #pragma unroll
      for (int ni = 0; ni < 4; ++ni) {
        int row = wc * 64 + ni * 16 + (lane & 15);
        int c = (ks * 4 + (lane >> 4)) ^ (row & 7);
        bq[ni] = *(const bf16x8*)(Bs + row * 128 + c * 16);
      }
      #pragma unroll
      for (int mi = 0; mi < 4; ++mi)
        #pragma unroll
        for (int ni = 0; ni < 4; ++ni)
          acc[mi][ni] = MFMA(af[mi], bq[ni], acc[mi][ni]);
    }
    __syncthreads();
  }

  #pragma unroll
  for (int mi = 0; mi < 4; ++mi) {
    #pragma unroll
    for (int ni = 0; ni < 4; ++ni) {
      const int col = bn + wc * 64 + ni * 16 + (lane & 15);
      const float bv = bias[col];
      #pragma unroll
      for (int j = 0; j < 4; ++j) {
        const int row = bm + wr * 64 + mi * 16 + ((lane >> 4) << 2) + j;
        const float v = acc[mi][ni][j] + bv;
        C[(size_t)row * N + col] = v;
      }
    }
  }
}

// ---------------- fused recurrence (r5, verbatim) + overlapped logits consumers ----------------
// 8064 blocks x 512 threads.
//   Blocks 0..31: layer 0 (32 cols each; waves = K-quarter x col-tile)   [r5]
//   Blocks 32..63: layer 1 (32 cols each; waves = K-half x matrix x ct)  [r5]
//   Blocks 64..8063: logits tiles 128x128, tile_m ascending; poll f1[thi], then GEMM
//     with A = H1 via coherent loads (no kernel-boundary acquire inside), B = embB.
#define NB0L 32
#define RL_NREC 64
#define LOG_TN 250
#define COMB_OFF 131072
#define LDS_TOTAL (COMB_OFF + 8192)
#define FLINE 128

__global__ __launch_bounds__(512) void rec_logits(
    const u16* __restrict__ Wh0T, const u16* __restrict__ Wx1T, const u16* __restrict__ Wh1T,
    const float* __restrict__ X0,       // 4096x1024 f32, includes b0
    const float* __restrict__ b1,
    const u16* __restrict__ h0init, const u16* __restrict__ h1init,
    u16* H0, u16* H1,                   // 4096x1024 bf16, coherent-exchanged
    const u16* __restrict__ embB, const float* __restrict__ outb,
    float* out,                         // d_out: logits at 0, hidden at +B*T*V
    char* flags)                        // 64KB: f0 at 0, f1 at +32KB
{
  __shared__ __align__(16) char lds[LDS_TOTAL];
  const int tid  = threadIdx.x;
  const int lane = tid & 63;
  const int w    = tid >> 6;           // 0..7
  const int l15  = lane & 15;
  const int lk   = lane >> 4;          // 0..3
  const int blk  = blockIdx.x;
  float* comb = (float*)(lds + COMB_OFF);
  char* f0 = flags;
  char* f1 = flags + 32768;
  float* hidOut = out + (size_t)BATCH * SEQ * VOCAB;

  if (blk >= RL_NREC) {
    // ---------------- logits consumer: one 128x128 tile ----------------
    const int lb = blk - RL_NREC;
    const int tm = lb / LOG_TN;
    const int tn = lb - tm * LOG_TN;
    const int bm = tm * 128, bn = tn * 128;
    const int thi = tm * 8 + 7;
    if (tid == 0) {
      const u32 pat = (u32)(thi + 1) * 0x10001u;
      while (!flags_ready(f1 + (size_t)thi * FLINE, pat)) __builtin_amdgcn_s_sleep(8);
    }
    __syncthreads();                     // H1 rows [0, bm+127] now device-visible

    char* As = lds;
    char* Bs = lds + 16384;
    const int wr = w >> 2, wc = w & 3;   // 2m x 4n wave grid, 64x32 out per wave
    const int srow = tid >> 3;           // 0..63
    const int sch  = (tid & 7) ^ (srow & 7);
    const u16* Bb  = embB + (size_t)(bn + srow) * EMB + sch * 8;
    const u16* Ab0 = H1 + (size_t)(bm + srow) * HID + sch * 8;
    const u16* Ab1 = H1 + (size_t)(bm + 64 + srow) * HID + sch * 8;
    char* Ad0 = As + srow * 128 + (tid & 7) * 16;
    char* Ad1 = As + (64 + srow) * 128 + (tid & 7) * 16;

    f32x4 acc[4][2];
    #pragma unroll
    for (int mi = 0; mi < 4; ++mi)
      #pragma unroll
      for (int ni = 0; ni < 2; ++ni) acc[mi][ni] = (f32x4){0.f, 0.f, 0.f, 0.f};

    for (int k0 = 0; k0 < EMB; k0 += 64) {
      #pragma unroll
      for (int i = 0; i < 2; ++i)
        __builtin_amdgcn_global_load_lds(
            (const __attribute__((address_space(1))) void*)(Bb + (size_t)i * 64 * EMB + k0),
            (__attribute__((address_space(3))) void*)(Bs + i * 8192 + w * 1024 + lane * 16),
            16, 0, 0);
      u32x4 ra0, ra1;
      load2_coh16(Ab0 + k0, Ab1 + k0, &ra0, &ra1);
      *(u32x4*)Ad0 = ra0;
      *(u32x4*)Ad1 = ra1;
      __syncthreads();
      #pragma unroll
      for (int ks = 0; ks < 2; ++ks) {
        bf16x8 af[4], bq[2];
        #pragma unroll
        for (int mi = 0; mi < 4; ++mi) {
          int row = wr * 64 + mi * 16 + l15;
          int c = (ks * 4 + lk) ^ (row & 7);
          af[mi] = *(const bf16x8*)(As + row * 128 + c * 16);
        }
        #pragma unroll
        for (int ni = 0; ni < 2; ++ni) {
          int row = wc * 32 + ni * 16 + l15;
          int c = (ks * 4 + lk) ^ (row & 7);
          bq[ni] = *(const bf16x8*)(Bs + row * 128 + c * 16);
        }
        #pragma unroll
        for (int mi = 0; mi < 4; ++mi)
          #pragma unroll
          for (int ni = 0; ni < 2; ++ni)
            acc[mi][ni] = MFMA(af[mi], bq[ni], acc[mi][ni]);
      }
      __syncthreads();
    }
    #pragma unroll
    for (int ni = 0; ni < 2; ++ni) {
      const int col = bn + wc * 32 + ni * 16 + l15;
      const float bv = outb[col];
      #pragma unroll
      for (int mi = 0; mi < 4; ++mi) {
        #pragma unroll
        for (int j = 0; j < 4; ++j) {
          const int row = bm + wr * 64 + mi * 16 + lk * 4 + j;
          out[(size_t)(row & 15) * ((size_t)SEQ * VOCAB)
              + (size_t)(row >> 4) * VOCAB + col] = acc[mi][ni][j] + bv;
        }
      }
    }
    return;
  }

  // ---------------- recurrence (round-5 structure, verbatim) ----------------
  const bool is0 = (blk < NB0L);

  if (is0) {
    const u16* src = Wh0T + (size_t)(blk * 32) * HID;
    for (int it = 0; it < 8; ++it) {
      int g = it * 512 + tid;                 // 0..4095
      int brow = g & 31, f = g >> 5;          // f 0..127
      *(bf16x8*)(lds + f * 512 + brow * 16) =
          *(const bf16x8*)(src + (size_t)brow * HID + f * 8);
    }
  } else {
    const u16* s0 = Wx1T + (size_t)((blk - NB0L) * 32) * HID;
    const u16* s1 = Wh1T + (size_t)((blk - NB0L) * 32) * HID;
    for (int it = 0; it < 8; ++it) {
      int g = it * 512 + tid;
      int brow = g & 31, f = g >> 5;
      int o = f * 512 + brow * 16;
      *(bf16x8*)(lds + o)         = *(const bf16x8*)(s0 + (size_t)brow * HID + f * 8);
      *(bf16x8*)(lds + 65536 + o) = *(const bf16x8*)(s1 + (size_t)brow * HID + f * 8);
    }
  }
  __syncthreads();

  if (is0) {
    const int q  = w >> 1;                    // K-quarter 0..3
    const int ct = w & 1;
    const int brow = ct * 16 + l15;
    const int col  = blk * 32 + brow;
    for (int s = 0; s < SEQ; ++s) {
      const u16* hsrc = (s == 0) ? h0init : (H0 + (size_t)(s - 1) * BATCH * HID);
      const char* ap = (const char*)hsrc + l15 * 2048 + q * 512 + lk * 16;
      bf16x8 a[8];
      load8_coh(ap, a);
      f32x4 ae = {0,0,0,0}, ao = {0,0,0,0};
      #pragma unroll
      for (int m = 0; m < 8; m += 2) {
        ae = MFMA(a[m],     *(const bf16x8*)(lds + (q*32 + m*4 + lk)*512 + brow*16), ae);
        ao = MFMA(a[m + 1], *(const bf16x8*)(lds + (q*32 + (m+1)*4 + lk)*512 + brow*16), ao);
      }
      f32x4 acc = ae + ao;
      if (w >= 2) *(f32x4*)(comb + ((size_t)w * 64 + lane) * 4) = acc;
      __syncthreads();
      if (w < 2) {
        float xv[4];
        #pragma unroll
        for (int j = 0; j < 4; ++j)
          xv[j] = X0[(size_t)(s * BATCH + lk * 4 + j) * HID + col];
        f32x4 p2 = *(const f32x4*)(comb + ((size_t)(w + 2) * 64 + lane) * 4);
        f32x4 p4 = *(const f32x4*)(comb + ((size_t)(w + 4) * 64 + lane) * 4);
        f32x4 p6 = *(const f32x4*)(comb + ((size_t)(w + 6) * 64 + lane) * 4);
        acc = (acc + p2) + (p4 + p6);
        #pragma unroll
        for (int j = 0; j < 4; ++j) {
          const int b = lk * 4 + j;
          float v = tanhf(acc[j] + xv[j]);
          store_u16_coh(H0 + (size_t)(s * BATCH + b) * HID + col, f2bf(v));
          if (s == SEQ - 1) hidOut[(size_t)b * HID + col] = v;
        }
        wait_vm0();
      }
      __syncthreads();                        // all h0(s) stores drained block-wide
      if (tid == 0) {
        store_u16_coh((u16*)(f0 + (size_t)s * FLINE) + blk, (u16)(s + 1));
        if (s + 1 < SEQ) {
          const u32 pat = (u32)(s + 1) * 0x10001u;
          while (!flags_ready(f0 + (size_t)s * FLINE, pat)) {}
        }
      }
      if (s + 1 < SEQ) __syncthreads();
    }
  } else {
    const int kh  = w >> 2;                   // K-half
    const int mat = (w >> 1) & 1;             // 0: Wx1 (vs h0(t)), 1: Wh1 (vs h1(t-1))
    const int ct  = w & 1;
    const int brow = ct * 16 + l15;
    const int col  = (blk - NB0L) * 32 + brow;
    const float bv = b1[col];
    const char* wb = lds + mat * 65536;
    if (tid == 0) { while (!flags_ready(f0, 0x10001u)) {} }   // wait h0(0)
    __syncthreads();
    for (int t = 0; t < SEQ; ++t) {
      const u16* hsrc = mat ? ((t == 0) ? h1init : (H1 + (size_t)(t - 1) * BATCH * HID))
                            : (H0 + (size_t)t * BATCH * HID);
      const char* ap = (const char*)hsrc + l15 * 2048 + kh * 1024 + lk * 16;
      bf16x8 a[16];
      load16_coh(ap, a);
      f32x4 ae = {0,0,0,0}, ao = {0,0,0,0};
      #pragma unroll
      for (int m = 0; m < 16; m += 2) {
        ae = MFMA(a[m],     *(const bf16x8*)(wb + (kh*64 + m*4 + lk)*512 + brow*16), ae);
        ao = MFMA(a[m + 1], *(const bf16x8*)(wb + (kh*64 + (m+1)*4 + lk)*512 + brow*16), ao);
      }
      f32x4 acc = ae + ao;
      if (w >= 2) *(f32x4*)(comb + ((size_t)w * 64 + lane) * 4) = acc;
      __syncthreads();
      if (w < 2) {
        f32x4 p2 = *(const f32x4*)(comb + ((size_t)(w + 2) * 64 + lane) * 4);
        f32x4 p4 = *(const f32x4*)(comb + ((size_t)(w + 4) * 64 + lane) * 4);
        f32x4 p6 = *(const f32x4*)(comb + ((size_t)(w + 6) * 64 + lane) * 4);
        acc = (acc + p2) + (p4 + p6);
        #pragma unroll
        for (int j = 0; j < 4; ++j) {
          const int b = lk * 4 + j;
          float v = tanhf(acc[j] + bv);
          store_u16_coh(H1 + (size_t)(t * BATCH + b) * HID + col, f2bf(v));
          if (t == SEQ - 1) hidOut[(size_t)(BATCH * HID) + (size_t)b * HID + col] = v;
        }
        wait_vm0();
      }
      __syncthreads();                        // all h1(t) stores drained block-wide
      if (tid == 0)
        store_u16_coh((u16*)(f1 + (size_t)t * FLINE) + (blk - NB0L), (u16)(t + 1));
      if (t + 1 < SEQ) {
        if (tid == 0) {
          const u32 pat = (u32)(t + 2) * 0x10001u;          // f0[t+1] ready?
          while (!flags_ready(f0 + (size_t)(t + 1) * FLINE, pat)) {}
        }
        if (tid == 64) {
          const u32 pat = (u32)(t + 1) * 0x10001u;          // f1[t] ready?
          while (!flags_ready(f1 + (size_t)t * FLINE, pat)) {}
        }
        __syncthreads();
      }
    }
  }
}

// ---------------- launch ----------------
extern "C" void kernel_launch(void* const* d_in, const int* in_sizes, int n_in,
                              void* d_out, int out_size, void* d_ws, size_t ws_size,
                              hipStream_t stream) {
  const int*   x      = (const int*)  d_in[0];
  const float* hidden = (const float*)d_in[1];
  const float* embW   = (const float*)d_in[2];
  const float* Wx0    = (const float*)d_in[3];
  const float* Wh0    = (const float*)d_in[4];
  const float* b0     = (const float*)d_in[5];
  const float* Wx1    = (const float*)d_in[6];
  const float* Wh1    = (const float*)d_in[7];
  const float* b1     = (const float*)d_in[8];
  const float* outb   = (const float*)d_in[9];
  float* out = (float*)d_out;

  char* ws = (char*)d_ws;
  size_t off = 0;
  auto alloc = [&](size_t bytes) {
    char* p = ws + off; off += (bytes + 255) & ~(size_t)255; return p;
  };
  u16*   embB = (u16*)  alloc((size_t)VOCAB * EMB * 2);
  u16*   Wx0T = (u16*)  alloc((size_t)EMB * HID * 2);
  u16*   Wh0T = (u16*)  alloc((size_t)HID * HID * 2);
  u16*   Wx1T = (u16*)  alloc((size_t)HID * HID * 2);
  u16*   Wh1T = (u16*)  alloc((size_t)HID * HID * 2);
  u16*   E    = (u16*)  alloc((size_t)MROWS * EMB * 2);
  float* X0f  = (float*)alloc((size_t)MROWS * HID * 4);
  u16*   H0   = (u16*)  alloc((size_t)MROWS * HID * 2);
  u16*   H1   = (u16*)  alloc((size_t)MROWS * HID * 2);
  u16*   h0i  = (u16*)  alloc((size_t)BATCH * HID * 2);
  u16*   h1i  = (u16*)  alloc((size_t)BATCH * HID * 2);
  char*  flags = (char*)alloc(65536);   // f0[256 lines] + f1[256 lines], 128B each
  if (off > ws_size) return;

  cvt_hidden<<<dim3(128), dim3(256), 0, stream>>>(hidden, h0i, h1i, (unsigned*)flags);

  dim3 tb(32, 8), tg(32, 32);
  transpose_cvt<<<tg, tb, 0, stream>>>(Wx0, Wx0T);
  transpose_cvt<<<tg, tb, 0, stream>>>(Wh0, Wh0T);
  transpose_cvt<<<tg, tb, 0, stream>>>(Wx1, Wx1T);
  transpose_cvt<<<tg, tb, 0, stream>>>(Wh1, Wh1T);

  cvt_emb<<<dim3(2048), dim3(256), 0, stream>>>(
      (const float4*)embW, (ushort4*)embB, (int)((size_t)VOCAB * EMB / 4));
  gather_emb<<<dim3(MROWS), dim3(256), 0, stream>>>(x, embW, E);

  // X0 = E @ Wx0^T + b0   (4096x1024)
  gemm_bt<0><<<dim3(HID / 128, MROWS / 128), dim3(256), 0, stream>>>(
      E, Wx0T, b0, X0f, MROWS, HID, EMB);

  // fused: recurrence (blocks 0..63) + overlapped logits consumers (blocks 64..8063)
  rec_logits<<<dim3(RL_NREC + 32 * LOG_TN), dim3(512), 0, stream>>>(
      Wh0T, Wx1T, Wh1T, X0f, b1, h0i, h1i, H0, H1, embB, outb, out, flags);
}

// Round 9
// 1466.054 us; speedup vs baseline: 1.8511x; 1.3443x over previous
//
#include <hip/hip_runtime.h>
#include <stdint.h>

#define VOCAB 32000
#define EMB   1024
#define HID   1024
#define BATCH 16
#define SEQ   256
#define MROWS (SEQ*BATCH)   // 4096

typedef unsigned short u16;
typedef uint32_t u32;
typedef __bf16 bf16x8 __attribute__((ext_vector_type(8)));
typedef float  f32x4  __attribute__((ext_vector_type(4)));
typedef u32    u32x4  __attribute__((ext_vector_type(4)));

static __device__ __forceinline__ u16 f2bf(float f) {
  union { float f; uint32_t u; } v; v.f = f;
  return (u16)((v.u + 0x7FFFu + ((v.u >> 16) & 1u)) >> 16);  // RNE
}

static __device__ __forceinline__ f32x4 MFMA(bf16x8 a, bf16x8 b, f32x4 c) {
  return __builtin_amdgcn_mfma_f32_16x16x32_bf16(a, b, c, 0, 0, 0);
}

// ---- coherent helpers (sc0 sc1 = device-scope, L1/L2-bypass) ----

// 8 tagged-u32x4 loads: frags m=0..3 at m*128 + {0,16}
static __device__ __forceinline__ void loadt8(const void* p, u32x4* r) {
  asm volatile(
    "global_load_dwordx4 %0, %8, off sc0 sc1\n\t"
    "global_load_dwordx4 %1, %8, off offset:16 sc0 sc1\n\t"
    "global_load_dwordx4 %2, %8, off offset:128 sc0 sc1\n\t"
    "global_load_dwordx4 %3, %8, off offset:144 sc0 sc1\n\t"
    "global_load_dwordx4 %4, %8, off offset:256 sc0 sc1\n\t"
    "global_load_dwordx4 %5, %8, off offset:272 sc0 sc1\n\t"
    "global_load_dwordx4 %6, %8, off offset:384 sc0 sc1\n\t"
    "global_load_dwordx4 %7, %8, off offset:400 sc0 sc1\n\t"
    "s_waitcnt vmcnt(0)"
    : "=&v"(r[0]), "=&v"(r[1]), "=&v"(r[2]), "=&v"(r[3]),
      "=&v"(r[4]), "=&v"(r[5]), "=&v"(r[6]), "=&v"(r[7])
    : "v"(p) : "memory");
}

// 16 tagged-u32x4 loads: frags m=0..7 at m*128 + {0,16}
static __device__ __forceinline__ void loadt16(const void* p, u32x4* r) {
  asm volatile(
    "global_load_dwordx4 %0, %16, off sc0 sc1\n\t"
    "global_load_dwordx4 %1, %16, off offset:16 sc0 sc1\n\t"
    "global_load_dwordx4 %2, %16, off offset:128 sc0 sc1\n\t"
    "global_load_dwordx4 %3, %16, off offset:144 sc0 sc1\n\t"
    "global_load_dwordx4 %4, %16, off offset:256 sc0 sc1\n\t"
    "global_load_dwordx4 %5, %16, off offset:272 sc0 sc1\n\t"
    "global_load_dwordx4 %6, %16, off offset:384 sc0 sc1\n\t"
    "global_load_dwordx4 %7, %16, off offset:400 sc0 sc1\n\t"
    "global_load_dwordx4 %8, %16, off offset:512 sc0 sc1\n\t"
    "global_load_dwordx4 %9, %16, off offset:528 sc0 sc1\n\t"
    "global_load_dwordx4 %10, %16, off offset:640 sc0 sc1\n\t"
    "global_load_dwordx4 %11, %16, off offset:656 sc0 sc1\n\t"
    "global_load_dwordx4 %12, %16, off offset:768 sc0 sc1\n\t"
    "global_load_dwordx4 %13, %16, off offset:784 sc0 sc1\n\t"
    "global_load_dwordx4 %14, %16, off offset:896 sc0 sc1\n\t"
    "global_load_dwordx4 %15, %16, off offset:912 sc0 sc1\n\t"
    "s_waitcnt vmcnt(0)"
    : "=&v"(r[0]), "=&v"(r[1]), "=&v"(r[2]), "=&v"(r[3]),
      "=&v"(r[4]), "=&v"(r[5]), "=&v"(r[6]), "=&v"(r[7]),
      "=&v"(r[8]), "=&v"(r[9]), "=&v"(r[10]), "=&v"(r[11]),
      "=&v"(r[12]), "=&v"(r[13]), "=&v"(r[14]), "=&v"(r[15])
    : "v"(p) : "memory");
}

// logits A-staging: 2 rows x 8 tagged u32 each
static __device__ __forceinline__ void load22(const void* p0, const void* p1, u32x4* r) {
  asm volatile(
    "global_load_dwordx4 %0, %4, off sc0 sc1\n\t"
    "global_load_dwordx4 %1, %4, off offset:16 sc0 sc1\n\t"
    "global_load_dwordx4 %2, %5, off sc0 sc1\n\t"
    "global_load_dwordx4 %3, %5, off offset:16 sc0 sc1\n\t"
    "s_waitcnt vmcnt(0)"
    : "=&v"(r[0]), "=&v"(r[1]), "=&v"(r[2]), "=&v"(r[3])
    : "v"(p0), "v"(p1) : "memory");
}

static __device__ __forceinline__ void store_u32_coh(u32* p, u32 v) {
  asm volatile("global_store_dword %0, %1, off sc0 sc1"
               :: "v"(p), "v"(v) : "memory");
}
static __device__ __forceinline__ void store_u16_coh(u16* p, u16 v) {
  asm volatile("global_store_short %0, %1, off sc0 sc1"
               :: "v"(p), "v"((u32)v) : "memory");
}
static __device__ __forceinline__ void wait_vm0() {
  asm volatile("s_waitcnt vmcnt(0)" ::: "memory");
}

// poll a 64B flag line (32 u16 slots)
static __device__ __forceinline__ int flags_ready(const void* p, u32 pat) {
  u32x4 a, b, c, d;
  asm volatile(
    "global_load_dwordx4 %0, %4, off sc0 sc1\n\t"
    "global_load_dwordx4 %1, %4, off offset:16 sc0 sc1\n\t"
    "global_load_dwordx4 %2, %4, off offset:32 sc0 sc1\n\t"
    "global_load_dwordx4 %3, %4, off offset:48 sc0 sc1\n\t"
    "s_waitcnt vmcnt(0)"
    : "=&v"(a), "=&v"(b), "=&v"(c), "=&v"(d)
    : "v"(p) : "memory");
  u32 m = (a[0]^pat)|(a[1]^pat)|(a[2]^pat)|(a[3]^pat)
        | (b[0]^pat)|(b[1]^pat)|(b[2]^pat)|(b[3]^pat)
        | (c[0]^pat)|(c[1]^pat)|(c[2]^pat)|(c[3]^pat)
        | (d[0]^pat)|(d[1]^pat)|(d[2]^pat)|(d[3]^pat);
  return m == 0u;
}

// pack 8 tagged u32 (low16 = bf16) into one bf16x8
static __device__ __forceinline__ bf16x8 packfrag(u32x4 e, u32x4 o) {
  u32x4 p;
  p[0] = (e[1] << 16) | (e[0] & 0xFFFFu);
  p[1] = (e[3] << 16) | (e[2] & 0xFFFFu);
  p[2] = (o[1] << 16) | (o[0] & 0xFFFFu);
  p[3] = (o[3] << 16) | (o[2] & 0xFFFFu);
  union { u32x4 u; bf16x8 b; } c; c.u = p; return c.b;
}

// ---------------- converts ----------------

__global__ void cvt_hidden(const float* __restrict__ hidden,
                           u16* __restrict__ h0i, u16* __restrict__ h1i,
                           unsigned* __restrict__ flags) {
  int i = blockIdx.x * 256 + threadIdx.x;
  if (i < 16384) flags[i] = 0u;
  if (i < BATCH * HID)            h0i[i] = f2bf(hidden[i]);
  else if (i < 2 * BATCH * HID)   h1i[i - BATCH * HID] = f2bf(hidden[i]);
}

__global__ void transpose_cvt(const float* __restrict__ in, u16* __restrict__ out) {
  __shared__ float tile[32][33];
  int bx = blockIdx.x * 32;   // N
  int by = blockIdx.y * 32;   // K
  int tx = threadIdx.x, ty = threadIdx.y;   // (32,8)
  #pragma unroll
  for (int i = 0; i < 32; i += 8)
    tile[ty + i][tx] = in[(size_t)(by + ty + i) * HID + bx + tx];
  __syncthreads();
  #pragma unroll
  for (int i = 0; i < 32; i += 8)
    out[(size_t)(bx + ty + i) * HID + by + tx] = f2bf(tile[tx][ty + i]);
}

__global__ void cvt_emb(const float4* __restrict__ in, ushort4* __restrict__ out, int n4) {
  int stride = gridDim.x * blockDim.x;
  for (int i = blockIdx.x * blockDim.x + threadIdx.x; i < n4; i += stride) {
    float4 v = in[i];
    ushort4 o; o.x = f2bf(v.x); o.y = f2bf(v.y); o.z = f2bf(v.z); o.w = f2bf(v.w);
    out[i] = o;
  }
}

__global__ void gather_emb(const int* __restrict__ x, const float* __restrict__ embW,
                           u16* __restrict__ E) {
  int r = blockIdx.x;               // 0..4095
  int b = r & 15, t = r >> 4;
  int idx = x[b * SEQ + t];
  const float4* src = (const float4*)(embW + (size_t)idx * EMB);
  ushort4* dst = (ushort4*)(E + (size_t)r * EMB);
  float4 v = src[threadIdx.x];
  ushort4 o; o.x = f2bf(v.x); o.y = f2bf(v.y); o.z = f2bf(v.z); o.w = f2bf(v.w);
  dst[threadIdx.x] = o;
}

// ---------------- 128x128 MFMA GEMM for X0 (C = A @ B^T + bias) ----------------
__global__ __launch_bounds__(256) void gemm_bt(
    const u16* __restrict__ A, const u16* __restrict__ B,
    const float* __restrict__ bias, float* __restrict__ C,
    int M, int N, int K)
{
  __shared__ __align__(16) char lds[32768];
  char* As = lds;
  char* Bs = lds + 16384;
  const int tid  = threadIdx.x;
  const int lane = tid & 63;
  const int wave = tid >> 6;
  const int wr = wave >> 1, wc = wave & 1;
  const int bm = blockIdx.y * 128;
  const int bn = blockIdx.x * 128;
  const int srow = tid >> 3;
  const int swc  = (tid & 7) ^ (srow & 7);

  f32x4 acc[4][4];
  #pragma unroll
  for (int i = 0; i < 4; ++i)
    #pragma unroll
    for (int j = 0; j < 4; ++j) acc[i][j] = (f32x4){0.f, 0.f, 0.f, 0.f};

  const u16* Ab = A + (size_t)(bm + srow) * K + swc * 8;
  const u16* Bb = B + (size_t)(bn + srow) * K + swc * 8;
  const size_t rstep = (size_t)32 * K;

  for (int k0 = 0; k0 < K; k0 += 64) {
    #pragma unroll
    for (int i = 0; i < 4; ++i) {
      __builtin_amdgcn_global_load_lds(
          (const __attribute__((address_space(1))) void*)(Ab + i * rstep + k0),
          (__attribute__((address_space(3))) void*)(As + i * 4096 + wave * 1024),
          16, 0, 0);
      __builtin_amdgcn_global_load_lds(
          (const __attribute__((address_space(1))) void*)(Bb + i * rstep + k0),
          (__attribute__((address_space(3))) void*)(Bs + i * 4096 + wave * 1024),
          16, 0, 0);
    }
    __syncthreads();
    #pragma unroll
    for (int ks = 0; ks < 2; ++ks) {
      bf16x8 af[4], bq[4];
      #pragma unroll
      for (int mi = 0; mi < 4; ++mi) {
        int row = wr * 64 + mi * 16 + (lane & 15);
        int c = (ks * 4 + (lane >> 4)) ^ (row & 7);
        af[mi] = *(const bf16x8*)(As + row * 128 + c * 16);
      }
      #pragma unroll
      for (int ni = 0; ni < 4; ++ni) {
        int row = wc * 64 + ni * 16 + (lane & 15);
        int c = (ks * 4 + (lane >> 4)) ^ (row & 7);
        bq[ni] = *(const bf16x8*)(Bs + row * 128 + c * 16);
      }
      #pragma unroll
      for (int mi = 0; mi < 4; ++mi)
        #pragma unroll
        for (int ni = 0; ni < 4; ++ni)
          acc[mi][ni] = MFMA(af[mi], bq[ni], acc[mi][ni]);
    }
    __syncthreads();
  }

  #pragma unroll
  for (int mi = 0; mi < 4; ++mi) {
    #pragma unroll
    for (int ni = 0; ni < 4; ++ni) {
      const int col = bn + wc * 64 + ni * 16 + (lane & 15);
      const float bv = bias[col];
      #pragma unroll
      for (int j = 0; j < 4; ++j) {
        const int row = bm + wr * 64 + mi * 16 + ((lane >> 4) << 2) + j;
        C[(size_t)row * N + col] = acc[mi][ni][j] + bv;
      }
    }
  }
}

// ---------------- fused recurrence (data-tagged h, no flags) + logits consumers ----------------
// H0u/H1u: u32 = (tag<<16)|bf16, tag = step+1; zeroed by hipMemsetAsync each launch.
// Blocks 0..31: layer 0, 32 cols each; 8 waves = K-eighths; finishers w<2 (cg=w).
// Blocks 32..63: layer 1, 32 cols each; 8 waves = matrix x K-quarter; finishers w<2.
// f1 flag lines (64B, 32 slots) published every 8th step for logits consumers only.
#define NB0L 32
#define RL_NREC 64
#define LOG_TN 250
#define COMB_OFF 131072
#define LDS_TOTAL (COMB_OFF + 16384)

__global__ __launch_bounds__(512) void rec_logits(
    const u16* __restrict__ Wh0T, const u16* __restrict__ Wx1T, const u16* __restrict__ Wh1T,
    const float* __restrict__ X0, const float* __restrict__ b1,
    const u16* __restrict__ h0init, const u16* __restrict__ h1init,
    u32* H0u, u32* H1u,
    const u16* __restrict__ embB, const float* __restrict__ outb,
    float* out, char* flags)
{
  __shared__ __align__(16) char lds[LDS_TOTAL];
  const int tid  = threadIdx.x;
  const int lane = tid & 63;
  const int w    = tid >> 6;           // 0..7
  const int l15  = lane & 15;
  const int lk   = lane >> 4;          // 0..3
  const int blk  = blockIdx.x;
  f32x4* cmb = (f32x4*)(lds + COMB_OFF);
  float* hidOut = out + (size_t)BATCH * SEQ * VOCAB;

  if (blk >= RL_NREC) {
    // ---------------- logits consumer: one 128x128 tile ----------------
    const int lb = blk - RL_NREC;
    const int tm = lb / LOG_TN;
    const int tn = lb - tm * LOG_TN;
    const int bm = tm * 128, bn = tn * 128;
    if (tid == 0) {
      const u32 pat = (u32)(tm + 1) * 0x10001u;
      while (!flags_ready(flags + (size_t)tm * 128, pat)) __builtin_amdgcn_s_sleep(8);
    }
    __syncthreads();                   // H1u rows for steps <= 8*tm+7 device-visible

    char* As = lds;
    char* Bs = lds + 16384;
    const int wr = w >> 2, wc = w & 3;
    const int srow = tid >> 3;         // 0..63
    const int sch  = (tid & 7) ^ (srow & 7);
    const u16* Bb  = embB + (size_t)(bn + srow) * EMB + sch * 8;
    const u32* Ab0 = H1u + (size_t)(bm + srow) * HID + sch * 8;
    const u32* Ab1 = H1u + (size_t)(bm + 64 + srow) * HID + sch * 8;
    char* Ad0 = As + srow * 128 + (tid & 7) * 16;
    char* Ad1 = As + (64 + srow) * 128 + (tid & 7) * 16;

    f32x4 acc[4][2];
    #pragma unroll
    for (int mi = 0; mi < 4; ++mi)
      #pragma unroll
      for (int ni = 0; ni < 2; ++ni) acc[mi][ni] = (f32x4){0.f, 0.f, 0.f, 0.f};

    for (int k0 = 0; k0 < EMB; k0 += 64) {
      #pragma unroll
      for (int i = 0; i < 2; ++i)
        __builtin_amdgcn_global_load_lds(
            (const __attribute__((address_space(1))) void*)(Bb + (size_t)i * 64 * EMB + k0),
            (__attribute__((address_space(3))) void*)(Bs + i * 8192 + w * 1024 + lane * 16),
            16, 0, 0);
      u32x4 ra[4];
      load22(Ab0 + k0, Ab1 + k0, ra);
      union { u32x4 u; bf16x8 b; } c0, c1;
      c0.b = packfrag(ra[0], ra[1]);
      c1.b = packfrag(ra[2], ra[3]);
      *(u32x4*)Ad0 = c0.u;
      *(u32x4*)Ad1 = c1.u;
      __syncthreads();
      #pragma unroll
      for (int ks = 0; ks < 2; ++ks) {
        bf16x8 af[4], bq[2];
        #pragma unroll
        for (int mi = 0; mi < 4; ++mi) {
          int row = wr * 64 + mi * 16 + l15;
          int c = (ks * 4 + lk) ^ (row & 7);
          af[mi] = *(const bf16x8*)(As + row * 128 + c * 16);
        }
        #pragma unroll
        for (int ni = 0; ni < 2; ++ni) {
          int row = wc * 32 + ni * 16 + l15;
          int c = (ks * 4 + lk) ^ (row & 7);
          bq[ni] = *(const bf16x8*)(Bs + row * 128 + c * 16);
        }
        #pragma unroll
        for (int mi = 0; mi < 4; ++mi)
          #pragma unroll
          for (int ni = 0; ni < 2; ++ni)
            acc[mi][ni] = MFMA(af[mi], bq[ni], acc[mi][ni]);
      }
      __syncthreads();
    }
    #pragma unroll
    for (int ni = 0; ni < 2; ++ni) {
      const int col = bn + wc * 32 + ni * 16 + l15;
      const float bv = outb[col];
      #pragma unroll
      for (int mi = 0; mi < 4; ++mi) {
        #pragma unroll
        for (int j = 0; j < 4; ++j) {
          const int row = bm + wr * 64 + mi * 16 + lk * 4 + j;
          out[(size_t)(row & 15) * ((size_t)SEQ * VOCAB)
              + (size_t)(row >> 4) * VOCAB + col] = acc[mi][ni][j] + bv;
        }
      }
    }
    return;
  }

  // ---------------- recurrence: stage weight slices into LDS ----------------
  const bool is0 = (blk < NB0L);
  if (is0) {
    const u16* src = Wh0T + (size_t)(blk * 32) * HID;
    for (int it = 0; it < 8; ++it) {
      int g = it * 512 + tid;                 // 0..4095
      int brow = g & 31, f = g >> 5;          // f 0..127
      *(bf16x8*)(lds + f * 512 + brow * 16) =
          *(const bf16x8*)(src + (size_t)brow * HID + f * 8);
    }
  } else {
    const u16* s0 = Wx1T + (size_t)((blk - NB0L) * 32) * HID;
    const u16* s1 = Wh1T + (size_t)((blk - NB0L) * 32) * HID;
    for (int it = 0; it < 8; ++it) {
      int g = it * 512 + tid;
      int brow = g & 31, f = g >> 5;
      int o = f * 512 + brow * 16;
      *(bf16x8*)(lds + o)         = *(const bf16x8*)(s0 + (size_t)brow * HID + f * 8);
      *(bf16x8*)(lds + 65536 + o) = *(const bf16x8*)(s1 + (size_t)brow * HID + f * 8);
    }
  }
  __syncthreads();

  if (is0) {
    // ---------------- layer 0: wave w = K-eighth ----------------
    const int col = blk * 32 + w * 16 + l15;        // finisher col (w<2)
    const char* H0b = (const char*)H0u + (size_t)l15 * 4096 + (size_t)w * 512 + lk * 32;
    for (int s = 0; s < SEQ; ++s) {
      float xv[4];
      if (w < 2) {
        #pragma unroll
        for (int j = 0; j < 4; ++j)
          xv[j] = X0[(size_t)(s * BATCH + lk * 4 + j) * HID + col];
      }
      bf16x8 a[4];
      if (s == 0) {
        const char* p = (const char*)h0init + l15 * 2048 + w * 256 + lk * 16;
        #pragma unroll
        for (int m = 0; m < 4; ++m) a[m] = *(const bf16x8*)(p + m * 64);
      } else {
        u32x4 r[8];
        const void* hb = H0b + (size_t)(s - 1) * 65536;
        const u32 tagw = (u32)s << 16;
        for (;;) {
          loadt8(hb, r);
          u32 acc = 0;
          #pragma unroll
          for (int i = 0; i < 8; ++i)
            #pragma unroll
            for (int j = 0; j < 4; ++j) acc |= r[i][j] ^ tagw;
          if (__all((acc & 0xFFFF0000u) == 0u)) break;
        }
        #pragma unroll
        for (int m = 0; m < 4; ++m) a[m] = packfrag(r[2 * m], r[2 * m + 1]);
      }
      f32x4 acc0 = {0,0,0,0}, acc1 = {0,0,0,0};
      #pragma unroll
      for (int m = 0; m < 4; ++m) {
        const int f = (w * 4 + m) * 4 + lk;
        acc0 = MFMA(a[m], *(const bf16x8*)(lds + f * 512 + l15 * 16),        acc0);
        acc1 = MFMA(a[m], *(const bf16x8*)(lds + f * 512 + (16 + l15) * 16), acc1);
      }
      cmb[(w * 2 + 0) * 64 + lane] = acc0;
      cmb[(w * 2 + 1) * 64 + lane] = acc1;
      __syncthreads();
      if (w < 2) {
        f32x4 r = (cmb[(0 * 2 + w) * 64 + lane] + cmb[(1 * 2 + w) * 64 + lane])
                + (cmb[(2 * 2 + w) * 64 + lane] + cmb[(3 * 2 + w) * 64 + lane])
                + (cmb[(4 * 2 + w) * 64 + lane] + cmb[(5 * 2 + w) * 64 + lane])
                + (cmb[(6 * 2 + w) * 64 + lane] + cmb[(7 * 2 + w) * 64 + lane]);
        #pragma unroll
        for (int j = 0; j < 4; ++j) {
          const int b = lk * 4 + j;
          float v = tanhf(r[j] + xv[j]);
          u32 word = ((u32)(s + 1) << 16) | (u32)f2bf(v);
          store_u32_coh(H0u + (size_t)(s * BATCH + b) * HID + col, word);
          if (s == SEQ - 1) hidOut[(size_t)b * HID + col] = v;
        }
      }
      __syncthreads();
    }
  } else {
    // ---------------- layer 1: wave = (matrix m2, K-quarter q) ----------------
    const int lblk = blk - NB0L;
    const int m2 = w >> 2;              // 0: Wx1 (vs h0(t)), 1: Wh1 (vs h1(t-1))
    const int q  = w & 3;
    const int col = lblk * 32 + w * 16 + l15;       // finisher col (w<2)
    const float bv = (w < 2) ? b1[col] : 0.f;
    const char* wb = lds + m2 * 65536;
    const size_t lbase = (size_t)l15 * 4096 + (size_t)q * 1024 + lk * 32;
    for (int t = 0; t < SEQ; ++t) {
      bf16x8 a[8];
      if (m2 == 1 && t == 0) {
        const char* p = (const char*)h1init + l15 * 2048 + q * 512 + lk * 16;
        #pragma unroll
        for (int m = 0; m < 8; ++m) a[m] = *(const bf16x8*)(p + m * 64);
      } else {
        const void* hb = (m2 == 0)
            ? (const void*)((const char*)H0u + (size_t)t * 65536 + lbase)
            : (const void*)((const char*)H1u + (size_t)(t - 1) * 65536 + lbase);
        const u32 tagw = (u32)(m2 == 0 ? t + 1 : t) << 16;
        u32x4 r[16];
        for (;;) {
          loadt16(hb, r);
          u32 acc = 0;
          #pragma unroll
          for (int i = 0; i < 16; ++i)
            #pragma unroll
            for (int j = 0; j < 4; ++j) acc |= r[i][j] ^ tagw;
          if (__all((acc & 0xFFFF0000u) == 0u)) break;
        }
        #pragma unroll
        for (int m = 0; m < 8; ++m) a[m] = packfrag(r[2 * m], r[2 * m + 1]);
      }
      f32x4 acc0 = {0,0,0,0}, acc1 = {0,0,0,0};
      #pragma unroll
      for (int m = 0; m < 8; ++m) {
        const int f = (q * 8 + m) * 4 + lk;
        acc0 = MFMA(a[m], *(const bf16x8*)(wb + f * 512 + l15 * 16),        acc0);
        acc1 = MFMA(a[m], *(const bf16x8*)(wb + f * 512 + (16 + l15) * 16), acc1);
      }
      cmb[(w * 2 + 0) * 64 + lane] = acc0;
      cmb[(w * 2 + 1) * 64 + lane] = acc1;
      __syncthreads();
      if (w < 2) {
        f32x4 r = (cmb[(0 * 2 + w) * 64 + lane] + cmb[(1 * 2 + w) * 64 + lane])
                + (cmb[(2 * 2 + w) * 64 + lane] + cmb[(3 * 2 + w) * 64 + lane])
                + (cmb[(4 * 2 + w) * 64 + lane] + cmb[(5 * 2 + w) * 64 + lane])
                + (cmb[(6 * 2 + w) * 64 + lane] + cmb[(7 * 2 + w) * 64 + lane]);
        #pragma unroll
        for (int j = 0; j < 4; ++j) {
          const int b = lk * 4 + j;
          float v = tanhf(r[j] + bv);
          u32 word = ((u32)(t + 1) << 16) | (u32)f2bf(v);
          store_u32_coh(H1u + (size_t)(t * BATCH + b) * HID + col, word);
          if (t == SEQ - 1)
            hidOut[(size_t)(BATCH * HID) + (size_t)b * HID + col] = v;
        }
        if ((t & 7) == 7) wait_vm0();   // drain before group flag publish
      }
      __syncthreads();
      if (((t & 7) == 7) && tid == 0)   // publish group g = t/8 for logits consumers
        store_u16_coh((u16*)(flags + (size_t)(t >> 3) * 128) + lblk, (u16)((t >> 3) + 1));
    }
  }
}

// ---------------- launch ----------------
extern "C" void kernel_launch(void* const* d_in, const int* in_sizes, int n_in,
                              void* d_out, int out_size, void* d_ws, size_t ws_size,
                              hipStream_t stream) {
  const int*   x      = (const int*)  d_in[0];
  const float* hidden = (const float*)d_in[1];
  const float* embW   = (const float*)d_in[2];
  const float* Wx0    = (const float*)d_in[3];
  const float* Wh0    = (const float*)d_in[4];
  const float* b0     = (const float*)d_in[5];
  const float* Wx1    = (const float*)d_in[6];
  const float* Wh1    = (const float*)d_in[7];
  const float* b1     = (const float*)d_in[8];
  const float* outb   = (const float*)d_in[9];
  float* out = (float*)d_out;

  char* ws = (char*)d_ws;
  size_t off = 0;
  auto alloc = [&](size_t bytes) {
    char* p = ws + off; off += (bytes + 255) & ~(size_t)255; return p;
  };
  u16*   embB = (u16*)  alloc((size_t)VOCAB * EMB * 2);
  u16*   Wx0T = (u16*)  alloc((size_t)EMB * HID * 2);
  u16*   Wh0T = (u16*)  alloc((size_t)HID * HID * 2);
  u16*   Wx1T = (u16*)  alloc((size_t)HID * HID * 2);
  u16*   Wh1T = (u16*)  alloc((size_t)HID * HID * 2);
  u16*   E    = (u16*)  alloc((size_t)MROWS * EMB * 2);
  float* X0f  = (float*)alloc((size_t)MROWS * HID * 4);
  u32*   H0u  = (u32*)  alloc((size_t)MROWS * HID * 4);
  u32*   H1u  = (u32*)  alloc((size_t)MROWS * HID * 4);
  u16*   h0i  = (u16*)  alloc((size_t)BATCH * HID * 2);
  u16*   h1i  = (u16*)  alloc((size_t)BATCH * HID * 2);
  char*  flags = (char*)alloc(65536);
  if (off > ws_size) return;

  cvt_hidden<<<dim3(128), dim3(256), 0, stream>>>(hidden, h0i, h1i, (unsigned*)flags);

  dim3 tb(32, 8), tg(32, 32);
  transpose_cvt<<<tg, tb, 0, stream>>>(Wx0, Wx0T);
  transpose_cvt<<<tg, tb, 0, stream>>>(Wh0, Wh0T);
  transpose_cvt<<<tg, tb, 0, stream>>>(Wx1, Wx1T);
  transpose_cvt<<<tg, tb, 0, stream>>>(Wh1, Wh1T);

  cvt_emb<<<dim3(2048), dim3(256), 0, stream>>>(
      (const float4*)embW, (ushort4*)embB, (int)((size_t)VOCAB * EMB / 4));
  gather_emb<<<dim3(MROWS), dim3(256), 0, stream>>>(x, embW, E);

  // X0 = E @ Wx0^T + b0   (4096x1024)
  gemm_bt<<<dim3(HID / 128, MROWS / 128), dim3(256), 0, stream>>>(
      E, Wx0T, b0, X0f, MROWS, HID, EMB);

  // clear data tags (prevents cross-replay memoization; graph-capture-safe)
  hipMemsetAsync(H0u, 0, (size_t)MROWS * HID * 4, stream);
  hipMemsetAsync(H1u, 0, (size_t)MROWS * HID * 4, stream);

  // fused: recurrence (blocks 0..63) + overlapped logits consumers
  rec_logits<<<dim3(RL_NREC + 32 * LOG_TN), dim3(512), 0, stream>>>(
      Wh0T, Wx1T, Wh1T, X0f, b1, h0i, h1i, H0u, H1u, embB, outb, out, flags);
}

// Round 10
// 1438.826 us; speedup vs baseline: 1.8862x; 1.0189x over previous
//
#include <hip/hip_runtime.h>
#include <stdint.h>

#define VOCAB 32000
#define EMB   1024
#define HID   1024
#define BATCH 16
#define SEQ   256
#define MROWS (SEQ*BATCH)   // 4096

typedef unsigned short u16;
typedef uint32_t u32;
typedef __bf16 bf16x8 __attribute__((ext_vector_type(8)));
typedef float  f32x4  __attribute__((ext_vector_type(4)));
typedef u32    u32x4  __attribute__((ext_vector_type(4)));

static __device__ __forceinline__ u16 f2bf(float f) {
  union { float f; uint32_t u; } v; v.f = f;
  return (u16)((v.u + 0x7FFFu + ((v.u >> 16) & 1u)) >> 16);  // RNE
}

static __device__ __forceinline__ f32x4 MFMA(bf16x8 a, bf16x8 b, f32x4 c) {
  return __builtin_amdgcn_mfma_f32_16x16x32_bf16(a, b, c, 0, 0, 0);
}

// ---- coherent helpers (sc0 sc1 = device-scope, L1/L2-bypass) ----

// 8 tagged-u32x4 loads: frags m=0..3 at m*128 + {0,16}
static __device__ __forceinline__ void loadt8(const void* p, u32x4* r) {
  asm volatile(
    "global_load_dwordx4 %0, %8, off sc0 sc1\n\t"
    "global_load_dwordx4 %1, %8, off offset:16 sc0 sc1\n\t"
    "global_load_dwordx4 %2, %8, off offset:128 sc0 sc1\n\t"
    "global_load_dwordx4 %3, %8, off offset:144 sc0 sc1\n\t"
    "global_load_dwordx4 %4, %8, off offset:256 sc0 sc1\n\t"
    "global_load_dwordx4 %5, %8, off offset:272 sc0 sc1\n\t"
    "global_load_dwordx4 %6, %8, off offset:384 sc0 sc1\n\t"
    "global_load_dwordx4 %7, %8, off offset:400 sc0 sc1\n\t"
    "s_waitcnt vmcnt(0)"
    : "=&v"(r[0]), "=&v"(r[1]), "=&v"(r[2]), "=&v"(r[3]),
      "=&v"(r[4]), "=&v"(r[5]), "=&v"(r[6]), "=&v"(r[7])
    : "v"(p) : "memory");
}

// 16 tagged-u32x4 loads: frags m=0..7 at m*128 + {0,16}
static __device__ __forceinline__ void loadt16(const void* p, u32x4* r) {
  asm volatile(
    "global_load_dwordx4 %0, %16, off sc0 sc1\n\t"
    "global_load_dwordx4 %1, %16, off offset:16 sc0 sc1\n\t"
    "global_load_dwordx4 %2, %16, off offset:128 sc0 sc1\n\t"
    "global_load_dwordx4 %3, %16, off offset:144 sc0 sc1\n\t"
    "global_load_dwordx4 %4, %16, off offset:256 sc0 sc1\n\t"
    "global_load_dwordx4 %5, %16, off offset:272 sc0 sc1\n\t"
    "global_load_dwordx4 %6, %16, off offset:384 sc0 sc1\n\t"
    "global_load_dwordx4 %7, %16, off offset:400 sc0 sc1\n\t"
    "global_load_dwordx4 %8, %16, off offset:512 sc0 sc1\n\t"
    "global_load_dwordx4 %9, %16, off offset:528 sc0 sc1\n\t"
    "global_load_dwordx4 %10, %16, off offset:640 sc0 sc1\n\t"
    "global_load_dwordx4 %11, %16, off offset:656 sc0 sc1\n\t"
    "global_load_dwordx4 %12, %16, off offset:768 sc0 sc1\n\t"
    "global_load_dwordx4 %13, %16, off offset:784 sc0 sc1\n\t"
    "global_load_dwordx4 %14, %16, off offset:896 sc0 sc1\n\t"
    "global_load_dwordx4 %15, %16, off offset:912 sc0 sc1\n\t"
    "s_waitcnt vmcnt(0)"
    : "=&v"(r[0]), "=&v"(r[1]), "=&v"(r[2]), "=&v"(r[3]),
      "=&v"(r[4]), "=&v"(r[5]), "=&v"(r[6]), "=&v"(r[7]),
      "=&v"(r[8]), "=&v"(r[9]), "=&v"(r[10]), "=&v"(r[11]),
      "=&v"(r[12]), "=&v"(r[13]), "=&v"(r[14]), "=&v"(r[15])
    : "v"(p) : "memory");
}

static __device__ __forceinline__ void store_u32_coh(u32* p, u32 v) {
  asm volatile("global_store_dword %0, %1, off sc0 sc1"
               :: "v"(p), "v"(v) : "memory");
}
static __device__ __forceinline__ void store_u16_coh(u16* p, u16 v) {
  asm volatile("global_store_short %0, %1, off sc0 sc1"
               :: "v"(p), "v"((u32)v) : "memory");
}
// 8B write-through store (repack output)
static __device__ __forceinline__ void store_u32x2_coh(void* p, u32 lo, u32 hi) {
  union { u32 u[2]; uint2 v; } t; t.u[0] = lo; t.u[1] = hi;
  asm volatile("global_store_dwordx2 %0, %1, off sc0 sc1"
               :: "v"(p), "v"(t.v) : "memory");
}
static __device__ __forceinline__ void wait_vm0() {
  asm volatile("s_waitcnt vmcnt(0)" ::: "memory");
}

// poll a 64B flag line (32 u16 slots)
static __device__ __forceinline__ int flags_ready(const void* p, u32 pat) {
  u32x4 a, b, c, d;
  asm volatile(
    "global_load_dwordx4 %0, %4, off sc0 sc1\n\t"
    "global_load_dwordx4 %1, %4, off offset:16 sc0 sc1\n\t"
    "global_load_dwordx4 %2, %4, off offset:32 sc0 sc1\n\t"
    "global_load_dwordx4 %3, %4, off offset:48 sc0 sc1\n\t"
    "s_waitcnt vmcnt(0)"
    : "=&v"(a), "=&v"(b), "=&v"(c), "=&v"(d)
    : "v"(p) : "memory");
  u32 m = (a[0]^pat)|(a[1]^pat)|(a[2]^pat)|(a[3]^pat)
        | (b[0]^pat)|(b[1]^pat)|(b[2]^pat)|(b[3]^pat)
        | (c[0]^pat)|(c[1]^pat)|(c[2]^pat)|(c[3]^pat)
        | (d[0]^pat)|(d[1]^pat)|(d[2]^pat)|(d[3]^pat);
  return m == 0u;
}

// single-dword coherent poll
static __device__ __forceinline__ int rdy_u32(const u32* p, u32 want) {
  u32 v;
  asm volatile("global_load_dword %0, %1, off sc0 sc1\n\ts_waitcnt vmcnt(0)"
               : "=v"(v) : "v"(p) : "memory");
  return v == want;
}

// pack 8 tagged u32 (low16 = bf16) into one bf16x8
static __device__ __forceinline__ bf16x8 packfrag(u32x4 e, u32x4 o) {
  u32x4 p;
  p[0] = (e[1] << 16) | (e[0] & 0xFFFFu);
  p[1] = (e[3] << 16) | (e[2] & 0xFFFFu);
  p[2] = (o[1] << 16) | (o[0] & 0xFFFFu);
  p[3] = (o[3] << 16) | (o[2] & 0xFFFFu);
  union { u32x4 u; bf16x8 b; } c; c.u = p; return c.b;
}

// ---------------- converts ----------------

__global__ void cvt_hidden(const float* __restrict__ hidden,
                           u16* __restrict__ h0i, u16* __restrict__ h1i,
                           unsigned* __restrict__ flags) {
  int i = blockIdx.x * 256 + threadIdx.x;
  if (i < 16384) flags[i] = 0u;
  if (i < BATCH * HID)            h0i[i] = f2bf(hidden[i]);
  else if (i < 2 * BATCH * HID)   h1i[i - BATCH * HID] = f2bf(hidden[i]);
}

__global__ void transpose_cvt(const float* __restrict__ in, u16* __restrict__ out) {
  __shared__ float tile[32][33];
  int bx = blockIdx.x * 32;   // N
  int by = blockIdx.y * 32;   // K
  int tx = threadIdx.x, ty = threadIdx.y;   // (32,8)
  #pragma unroll
  for (int i = 0; i < 32; i += 8)
    tile[ty + i][tx] = in[(size_t)(by + ty + i) * HID + bx + tx];
  __syncthreads();
  #pragma unroll
  for (int i = 0; i < 32; i += 8)
    out[(size_t)(bx + ty + i) * HID + by + tx] = f2bf(tile[tx][ty + i]);
}

__global__ void cvt_emb(const float4* __restrict__ in, ushort4* __restrict__ out, int n4) {
  int stride = gridDim.x * blockDim.x;
  for (int i = blockIdx.x * blockDim.x + threadIdx.x; i < n4; i += stride) {
    float4 v = in[i];
    ushort4 o; o.x = f2bf(v.x); o.y = f2bf(v.y); o.z = f2bf(v.z); o.w = f2bf(v.w);
    out[i] = o;
  }
}

__global__ void gather_emb(const int* __restrict__ x, const float* __restrict__ embW,
                           u16* __restrict__ E) {
  int r = blockIdx.x;               // 0..4095
  int b = r & 15, t = r >> 4;
  int idx = x[b * SEQ + t];
  const float4* src = (const float4*)(embW + (size_t)idx * EMB);
  ushort4* dst = (ushort4*)(E + (size_t)r * EMB);
  float4 v = src[threadIdx.x];
  ushort4 o; o.x = f2bf(v.x); o.y = f2bf(v.y); o.z = f2bf(v.z); o.w = f2bf(v.w);
  dst[threadIdx.x] = o;
}

// ---------------- 128x128 MFMA GEMM for X0 (C = A @ B^T + bias) ----------------
__global__ __launch_bounds__(256) void gemm_bt(
    const u16* __restrict__ A, const u16* __restrict__ B,
    const float* __restrict__ bias, float* __restrict__ C,
    int M, int N, int K)
{
  __shared__ __align__(16) char lds[32768];
  char* As = lds;
  char* Bs = lds + 16384;
  const int tid  = threadIdx.x;
  const int lane = tid & 63;
  const int wave = tid >> 6;
  const int wr = wave >> 1, wc = wave & 1;
  const int bm = blockIdx.y * 128;
  const int bn = blockIdx.x * 128;
  const int srow = tid >> 3;
  const int swc  = (tid & 7) ^ (srow & 7);

  f32x4 acc[4][4];
  #pragma unroll
  for (int i = 0; i < 4; ++i)
    #pragma unroll
    for (int j = 0; j < 4; ++j) acc[i][j] = (f32x4){0.f, 0.f, 0.f, 0.f};

  const u16* Ab = A + (size_t)(bm + srow) * K + swc * 8;
  const u16* Bb = B + (size_t)(bn + srow) * K + swc * 8;
  const size_t rstep = (size_t)32 * K;

  for (int k0 = 0; k0 < K; k0 += 64) {
    #pragma unroll
    for (int i = 0; i < 4; ++i) {
      __builtin_amdgcn_global_load_lds(
          (const __attribute__((address_space(1))) void*)(Ab + i * rstep + k0),
          (__attribute__((address_space(3))) void*)(As + i * 4096 + wave * 1024),
          16, 0, 0);
      __builtin_amdgcn_global_load_lds(
          (const __attribute__((address_space(1))) void*)(Bb + i * rstep + k0),
          (__attribute__((address_space(3))) void*)(Bs + i * 4096 + wave * 1024),
          16, 0, 0);
    }
    __syncthreads();
    #pragma unroll
    for (int ks = 0; ks < 2; ++ks) {
      bf16x8 af[4], bq[4];
      #pragma unroll
      for (int mi = 0; mi < 4; ++mi) {
        int row = wr * 64 + mi * 16 + (lane & 15);
        int c = (ks * 4 + (lane >> 4)) ^ (row & 7);
        af[mi] = *(const bf16x8*)(As + row * 128 + c * 16);
      }
      #pragma unroll
      for (int ni = 0; ni < 4; ++ni) {
        int row = wc * 64 + ni * 16 + (lane & 15);
        int c = (ks * 4 + (lane >> 4)) ^ (row & 7);
        bq[ni] = *(const bf16x8*)(Bs + row * 128 + c * 16);
      }
      #pragma unroll
      for (int mi = 0; mi < 4; ++mi)
        #pragma unroll
        for (int ni = 0; ni < 4; ++ni)
          acc[mi][ni] = MFMA(af[mi], bq[ni], acc[mi][ni]);
    }
    __syncthreads();
  }

  #pragma unroll
  for (int mi = 0; mi < 4; ++mi) {
    #pragma unroll
    for (int ni = 0; ni < 4; ++ni) {
      const int col = bn + wc * 64 + ni * 16 + (lane & 15);
      const float bv = bias[col];
      #pragma unroll
      for (int j = 0; j < 4; ++j) {
        const int row = bm + wr * 64 + mi * 16 + ((lane >> 4) << 2) + j;
        C[(size_t)row * N + col] = acc[mi][ni][j] + bv;
      }
    }
  }
}

// ---------------- fused: recurrence (r9 verbatim) + repack layer + cached logits ----------------
// Blocks 0..63: recurrence (data-tagged h, r9).
// Blocks 64..95: repack group g = blk-64: poll f1[g] (8 steps done), strip tags
//   H1u rows [128g,128g+128) -> bf16 H1b (sc0sc1 write-through), publish rf[g].
// Blocks 96..8095: logits tile 128x128; poll rf[tm] (1 dword), then fully cached
//   GEMM: A = H1b, B = embB via global_load_lds (no coherent data traffic).
#define NB0L 32
#define RL_NREC 64
#define NREPACK 32
#define LOG_TN 250
#define COMB_OFF 131072
#define LDS_TOTAL (COMB_OFF + 16384)

__global__ __launch_bounds__(512) void rec_logits(
    const u16* __restrict__ Wh0T, const u16* __restrict__ Wx1T, const u16* __restrict__ Wh1T,
    const float* __restrict__ X0, const float* __restrict__ b1,
    const u16* __restrict__ h0init, const u16* __restrict__ h1init,
    u32* H0u, u32* H1u, u16* H1b,
    const u16* __restrict__ embB, const float* __restrict__ outb,
    float* out, char* flags)
{
  __shared__ __align__(16) char lds[LDS_TOTAL];
  const int tid  = threadIdx.x;
  const int lane = tid & 63;
  const int w    = tid >> 6;           // 0..7
  const int l15  = lane & 15;
  const int lk   = lane >> 4;          // 0..3
  const int blk  = blockIdx.x;
  f32x4* cmb = (f32x4*)(lds + COMB_OFF);
  float* hidOut = out + (size_t)BATCH * SEQ * VOCAB;
  u32* rf = (u32*)(flags + 32768);     // rf[g] at stride 32 u32 (128B lines)

  if (blk >= RL_NREC + NREPACK) {
    // ---------------- logits consumer: one 128x128 tile, fully cached ----------------
    const int lb = blk - RL_NREC - NREPACK;
    const int tm = lb / LOG_TN;
    const int tn = lb - tm * LOG_TN;
    const int bm = tm * 128, bn = tn * 128;
    if (tid == 0) {
      while (!rdy_u32(rf + (size_t)tm * 32, (u32)(tm + 1))) __builtin_amdgcn_s_sleep(8);
    }
    __syncthreads();                   // H1b rows [0, bm+127] repacked & L3-visible

    char* As = lds;
    char* Bs = lds + 16384;
    const int wr = w >> 2, wc = w & 3;
    const int srow = tid >> 3;         // 0..63
    const int sch  = (tid & 7) ^ (srow & 7);
    const u16* Bb = embB + (size_t)(bn + srow) * EMB + sch * 8;
    const u16* Ab = H1b  + (size_t)(bm + srow) * HID + sch * 8;

    f32x4 acc[4][2];
    #pragma unroll
    for (int mi = 0; mi < 4; ++mi)
      #pragma unroll
      for (int ni = 0; ni < 2; ++ni) acc[mi][ni] = (f32x4){0.f, 0.f, 0.f, 0.f};

    for (int k0 = 0; k0 < EMB; k0 += 64) {
      #pragma unroll
      for (int i = 0; i < 2; ++i) {
        __builtin_amdgcn_global_load_lds(
            (const __attribute__((address_space(1))) void*)(Bb + (size_t)i * 64 * EMB + k0),
            (__attribute__((address_space(3))) void*)(Bs + i * 8192 + w * 1024),
            16, 0, 0);
        __builtin_amdgcn_global_load_lds(
            (const __attribute__((address_space(1))) void*)(Ab + (size_t)i * 64 * HID + k0),
            (__attribute__((address_space(3))) void*)(As + i * 8192 + w * 1024),
            16, 0, 0);
      }
      __syncthreads();
      #pragma unroll
      for (int ks = 0; ks < 2; ++ks) {
        bf16x8 af[4], bq[2];
        #pragma unroll
        for (int mi = 0; mi < 4; ++mi) {
          int row = wr * 64 + mi * 16 + l15;
          int c = (ks * 4 + lk) ^ (row & 7);
          af[mi] = *(const bf16x8*)(As + row * 128 + c * 16);
        }
        #pragma unroll
        for (int ni = 0; ni < 2; ++ni) {
          int row = wc * 32 + ni * 16 + l15;
          int c = (ks * 4 + lk) ^ (row & 7);
          bq[ni] = *(const bf16x8*)(Bs + row * 128 + c * 16);
        }
        #pragma unroll
        for (int mi = 0; mi < 4; ++mi)
          #pragma unroll
          for (int ni = 0; ni < 2; ++ni)
            acc[mi][ni] = MFMA(af[mi], bq[ni], acc[mi][ni]);
      }
      __syncthreads();
    }
    #pragma unroll
    for (int ni = 0; ni < 2; ++ni) {
      const int col = bn + wc * 32 + ni * 16 + l15;
      const float bv = outb[col];
      #pragma unroll
      for (int mi = 0; mi < 4; ++mi) {
        #pragma unroll
        for (int j = 0; j < 4; ++j) {
          const int row = bm + wr * 64 + mi * 16 + lk * 4 + j;
          out[(size_t)(row & 15) * ((size_t)SEQ * VOCAB)
              + (size_t)(row >> 4) * VOCAB + col] = acc[mi][ni][j] + bv;
        }
      }
    }
    return;
  }

  if (blk >= RL_NREC) {
    // ---------------- repack: group g (steps 8g..8g+7 -> H1 rows 128g..128g+127) ----
    const int g = blk - RL_NREC;
    if (tid == 0) {
      const u32 pat = (u32)(g + 1) * 0x10001u;
      while (!flags_ready(flags + (size_t)g * 128, pat)) __builtin_amdgcn_s_sleep(2);
    }
    __syncthreads();                   // tagged H1u rows drained to coherence point
    const u32* src = H1u + (size_t)g * 128 * 1024;
    u16* dst = H1b + (size_t)g * 128 * 1024;
    #pragma unroll 4
    for (int i = 0; i < 64; ++i) {
      int c = i * 512 + tid;           // u32x4 chunk index
      u32x4 v = *(const u32x4*)(src + (size_t)c * 4);   // plain cached load (safe: see notes)
      u32 lo = (v[0] & 0xFFFFu) | (v[1] << 16);
      u32 hi = (v[2] & 0xFFFFu) | (v[3] << 16);
      store_u32x2_coh(dst + (size_t)c * 4, lo, hi);     // write-through
    }
    wait_vm0();
    __syncthreads();
    if (tid == 0) store_u32_coh(rf + (size_t)g * 32, (u32)(g + 1));
    return;
  }

  // ---------------- recurrence (r9 verbatim) ----------------
  const bool is0 = (blk < NB0L);
  if (is0) {
    const u16* src = Wh0T + (size_t)(blk * 32) * HID;
    for (int it = 0; it < 8; ++it) {
      int g = it * 512 + tid;                 // 0..4095
      int brow = g & 31, f = g >> 5;          // f 0..127
      *(bf16x8*)(lds + f * 512 + brow * 16) =
          *(const bf16x8*)(src + (size_t)brow * HID + f * 8);
    }
  } else {
    const u16* s0 = Wx1T + (size_t)((blk - NB0L) * 32) * HID;
    const u16* s1 = Wh1T + (size_t)((blk - NB0L) * 32) * HID;
    for (int it = 0; it < 8; ++it) {
      int g = it * 512 + tid;
      int brow = g & 31, f = g >> 5;
      int o = f * 512 + brow * 16;
      *(bf16x8*)(lds + o)         = *(const bf16x8*)(s0 + (size_t)brow * HID + f * 8);
      *(bf16x8*)(lds + 65536 + o) = *(const bf16x8*)(s1 + (size_t)brow * HID + f * 8);
    }
  }
  __syncthreads();

  if (is0) {
    // layer 0: wave w = K-eighth
    const int col = blk * 32 + w * 16 + l15;        // finisher col (w<2)
    const char* H0b = (const char*)H0u + (size_t)l15 * 4096 + (size_t)w * 512 + lk * 32;
    for (int s = 0; s < SEQ; ++s) {
      float xv[4];
      if (w < 2) {
        #pragma unroll
        for (int j = 0; j < 4; ++j)
          xv[j] = X0[(size_t)(s * BATCH + lk * 4 + j) * HID + col];
      }
      bf16x8 a[4];
      if (s == 0) {
        const char* p = (const char*)h0init + l15 * 2048 + w * 256 + lk * 16;
        #pragma unroll
        for (int m = 0; m < 4; ++m) a[m] = *(const bf16x8*)(p + m * 64);
      } else {
        u32x4 r[8];
        const void* hb = H0b + (size_t)(s - 1) * 65536;
        const u32 tagw = (u32)s << 16;
        for (;;) {
          loadt8(hb, r);
          u32 acc = 0;
          #pragma unroll
          for (int i = 0; i < 8; ++i)
            #pragma unroll
            for (int j = 0; j < 4; ++j) acc |= r[i][j] ^ tagw;
          if (__all((acc & 0xFFFF0000u) == 0u)) break;
        }
        #pragma unroll
        for (int m = 0; m < 4; ++m) a[m] = packfrag(r[2 * m], r[2 * m + 1]);
      }
      f32x4 acc0 = {0,0,0,0}, acc1 = {0,0,0,0};
      #pragma unroll
      for (int m = 0; m < 4; ++m) {
        const int f = (w * 4 + m) * 4 + lk;
        acc0 = MFMA(a[m], *(const bf16x8*)(lds + f * 512 + l15 * 16),        acc0);
        acc1 = MFMA(a[m], *(const bf16x8*)(lds + f * 512 + (16 + l15) * 16), acc1);
      }
      cmb[(w * 2 + 0) * 64 + lane] = acc0;
      cmb[(w * 2 + 1) * 64 + lane] = acc1;
      __syncthreads();
      if (w < 2) {
        f32x4 r = (cmb[(0 * 2 + w) * 64 + lane] + cmb[(1 * 2 + w) * 64 + lane])
                + (cmb[(2 * 2 + w) * 64 + lane] + cmb[(3 * 2 + w) * 64 + lane])
                + (cmb[(4 * 2 + w) * 64 + lane] + cmb[(5 * 2 + w) * 64 + lane])
                + (cmb[(6 * 2 + w) * 64 + lane] + cmb[(7 * 2 + w) * 64 + lane]);
        #pragma unroll
        for (int j = 0; j < 4; ++j) {
          const int b = lk * 4 + j;
          float v = tanhf(r[j] + xv[j]);
          u32 word = ((u32)(s + 1) << 16) | (u32)f2bf(v);
          store_u32_coh(H0u + (size_t)(s * BATCH + b) * HID + col, word);
          if (s == SEQ - 1) hidOut[(size_t)b * HID + col] = v;
        }
      }
      __syncthreads();
    }
  } else {
    // layer 1: wave = (matrix m2, K-quarter q)
    const int lblk = blk - NB0L;
    const int m2 = w >> 2;              // 0: Wx1 (vs h0(t)), 1: Wh1 (vs h1(t-1))
    const int q  = w & 3;
    const int col = lblk * 32 + w * 16 + l15;       // finisher col (w<2)
    const float bv = (w < 2) ? b1[col] : 0.f;
    const char* wb = lds + m2 * 65536;
    const size_t lbase = (size_t)l15 * 4096 + (size_t)q * 1024 + lk * 32;
    for (int t = 0; t < SEQ; ++t) {
      bf16x8 a[8];
      if (m2 == 1 && t == 0) {
        const char* p = (const char*)h1init + l15 * 2048 + q * 512 + lk * 16;
        #pragma unroll
        for (int m = 0; m < 8; ++m) a[m] = *(const bf16x8*)(p + m * 64);
      } else {
        const void* hb = (m2 == 0)
            ? (const void*)((const char*)H0u + (size_t)t * 65536 + lbase)
            : (const void*)((const char*)H1u + (size_t)(t - 1) * 65536 + lbase);
        const u32 tagw = (u32)(m2 == 0 ? t + 1 : t) << 16;
        u32x4 r[16];
        for (;;) {
          loadt16(hb, r);
          u32 acc = 0;
          #pragma unroll
          for (int i = 0; i < 16; ++i)
            #pragma unroll
            for (int j = 0; j < 4; ++j) acc |= r[i][j] ^ tagw;
          if (__all((acc & 0xFFFF0000u) == 0u)) break;
        }
        #pragma unroll
        for (int m = 0; m < 8; ++m) a[m] = packfrag(r[2 * m], r[2 * m + 1]);
      }
      f32x4 acc0 = {0,0,0,0}, acc1 = {0,0,0,0};
      #pragma unroll
      for (int m = 0; m < 8; ++m) {
        const int f = (q * 8 + m) * 4 + lk;
        acc0 = MFMA(a[m], *(const bf16x8*)(wb + f * 512 + l15 * 16),        acc0);
        acc1 = MFMA(a[m], *(const bf16x8*)(wb + f * 512 + (16 + l15) * 16), acc1);
      }
      cmb[(w * 2 + 0) * 64 + lane] = acc0;
      cmb[(w * 2 + 1) * 64 + lane] = acc1;
      __syncthreads();
      if (w < 2) {
        f32x4 r = (cmb[(0 * 2 + w) * 64 + lane] + cmb[(1 * 2 + w) * 64 + lane])
                + (cmb[(2 * 2 + w) * 64 + lane] + cmb[(3 * 2 + w) * 64 + lane])
                + (cmb[(4 * 2 + w) * 64 + lane] + cmb[(5 * 2 + w) * 64 + lane])
                + (cmb[(6 * 2 + w) * 64 + lane] + cmb[(7 * 2 + w) * 64 + lane]);
        #pragma unroll
        for (int j = 0; j < 4; ++j) {
          const int b = lk * 4 + j;
          float v = tanhf(r[j] + bv);
          u32 word = ((u32)(t + 1) << 16) | (u32)f2bf(v);
          store_u32_coh(H1u + (size_t)(t * BATCH + b) * HID + col, word);
          if (t == SEQ - 1)
            hidOut[(size_t)(BATCH * HID) + (size_t)b * HID + col] = v;
        }
        if ((t & 7) == 7) wait_vm0();   // drain before group flag publish
      }
      __syncthreads();
      if (((t & 7) == 7) && tid == 0)   // publish group g = t/8 for repack blocks
        store_u16_coh((u16*)(flags + (size_t)(t >> 3) * 128) + lblk, (u16)((t >> 3) + 1));
    }
  }
}

// ---------------- launch ----------------
extern "C" void kernel_launch(void* const* d_in, const int* in_sizes, int n_in,
                              void* d_out, int out_size, void* d_ws, size_t ws_size,
                              hipStream_t stream) {
  const int*   x      = (const int*)  d_in[0];
  const float* hidden = (const float*)d_in[1];
  const float* embW   = (const float*)d_in[2];
  const float* Wx0    = (const float*)d_in[3];
  const float* Wh0    = (const float*)d_in[4];
  const float* b0     = (const float*)d_in[5];
  const float* Wx1    = (const float*)d_in[6];
  const float* Wh1    = (const float*)d_in[7];
  const float* b1     = (const float*)d_in[8];
  const float* outb   = (const float*)d_in[9];
  float* out = (float*)d_out;

  char* ws = (char*)d_ws;
  size_t off = 0;
  auto alloc = [&](size_t bytes) {
    char* p = ws + off; off += (bytes + 255) & ~(size_t)255; return p;
  };
  u16*   embB = (u16*)  alloc((size_t)VOCAB * EMB * 2);
  u16*   Wx0T = (u16*)  alloc((size_t)EMB * HID * 2);
  u16*   Wh0T = (u16*)  alloc((size_t)HID * HID * 2);
  u16*   Wx1T = (u16*)  alloc((size_t)HID * HID * 2);
  u16*   Wh1T = (u16*)  alloc((size_t)HID * HID * 2);
  u16*   E    = (u16*)  alloc((size_t)MROWS * EMB * 2);
  float* X0f  = (float*)alloc((size_t)MROWS * HID * 4);
  u32*   H0u  = (u32*)  alloc((size_t)MROWS * HID * 4);
  u32*   H1u  = (u32*)  alloc((size_t)MROWS * HID * 4);
  u16*   H1b  = (u16*)  alloc((size_t)MROWS * HID * 2);
  u16*   h0i  = (u16*)  alloc((size_t)BATCH * HID * 2);
  u16*   h1i  = (u16*)  alloc((size_t)BATCH * HID * 2);
  char*  flags = (char*)alloc(65536);
  if (off > ws_size) return;

  cvt_hidden<<<dim3(128), dim3(256), 0, stream>>>(hidden, h0i, h1i, (unsigned*)flags);

  dim3 tb(32, 8), tg(32, 32);
  transpose_cvt<<<tg, tb, 0, stream>>>(Wx0, Wx0T);
  transpose_cvt<<<tg, tb, 0, stream>>>(Wh0, Wh0T);
  transpose_cvt<<<tg, tb, 0, stream>>>(Wx1, Wx1T);
  transpose_cvt<<<tg, tb, 0, stream>>>(Wh1, Wh1T);

  cvt_emb<<<dim3(2048), dim3(256), 0, stream>>>(
      (const float4*)embW, (ushort4*)embB, (int)((size_t)VOCAB * EMB / 4));
  gather_emb<<<dim3(MROWS), dim3(256), 0, stream>>>(x, embW, E);

  // X0 = E @ Wx0^T + b0   (4096x1024)
  gemm_bt<<<dim3(HID / 128, MROWS / 128), dim3(256), 0, stream>>>(
      E, Wx0T, b0, X0f, MROWS, HID, EMB);

  // clear data tags (prevents cross-replay memoization; graph-capture-safe)
  hipMemsetAsync(H0u, 0, (size_t)MROWS * HID * 4, stream);
  hipMemsetAsync(H1u, 0, (size_t)MROWS * HID * 4, stream);

  // fused: recurrence (0..63) + repack (64..95) + cached logits consumers (96..8095)
  rec_logits<<<dim3(RL_NREC + NREPACK + 32 * LOG_TN), dim3(512), 0, stream>>>(
      Wh0T, Wx1T, Wh1T, X0f, b1, h0i, h1i, H0u, H1u, H1b, embB, outb, out, flags);
}